// Round 1
// baseline (1123.552 us; speedup 1.0000x reference)
//
#include <hip/hip_runtime.h>

using u16 = unsigned short;
using u32 = unsigned int;
using bf16x8 = __attribute__((ext_vector_type(8))) __bf16;
using f32x4  = __attribute__((ext_vector_type(4))) float;
using u16x8  = __attribute__((ext_vector_type(8))) u16;

#define DEV static __device__ __forceinline__

DEV float bf2f(u16 u) { union { u32 i; float f; } c; c.i = ((u32)u) << 16; return c.f; }
DEV u16 f2bf(float f) {
  union { float f; u32 i; } c; c.f = f;
  u32 r = c.i + 0x7FFFu + ((c.i >> 16) & 1u);
  return (u16)(r >> 16);
}

// async global->LDS, 16B per lane; lds dest must be wave-uniform base (HW adds lane*16)
DEV void gload_lds16(const void* g, void* l) {
  __builtin_amdgcn_global_load_lds(
      (const __attribute__((address_space(1))) u32*)g,
      (__attribute__((address_space(3))) u32*)l, 16, 0, 0);
}

// ---------------- cast x: fp32 -> bf16, 8 elems/thread ----------------
__global__ __launch_bounds__(256) void cast_x_kernel(const float* __restrict__ x,
                                                     u16* __restrict__ xb) {
  size_t i = (size_t)blockIdx.x * 256 + threadIdx.x;  // 2,097,152 threads exact
  const float4* s4 = (const float4*)(x + i * 8);
  float4 a = s4[0], c = s4[1];
  u16x8 o;
  o[0] = f2bf(a.x); o[1] = f2bf(a.y); o[2] = f2bf(a.z); o[3] = f2bf(a.w);
  o[4] = f2bf(c.x); o[5] = f2bf(c.y); o[6] = f2bf(c.z); o[7] = f2bf(c.w);
  *(u16x8*)(xb + i * 8) = o;
}

// ------------- W [K,N] fp32 -> Wt [N,K] bf16, tiled LDS transpose -------------
__global__ __launch_bounds__(256) void transpose_cast(const float* __restrict__ W,
                                                      u16* __restrict__ Wt, int K, int N) {
  __shared__ float t[32][33];
  int tx = threadIdx.x & 31, ty = threadIdx.x >> 5;
  int n0 = blockIdx.x * 32, k0 = blockIdx.y * 32;
#pragma unroll
  for (int i = 0; i < 4; ++i)
    t[ty + i * 8][tx] = W[(size_t)(k0 + ty + i * 8) * N + n0 + tx];
  __syncthreads();
#pragma unroll
  for (int i = 0; i < 4; ++i)
    Wt[(size_t)(n0 + ty + i * 8) * K + k0 + tx] = f2bf(t[tx][ty + i * 8]);
}

// ---------------- GEMM: C[M,N] = A[M,K] * Bt[N,K]^T (m97 structure) ----------------
// 128x128 tile, BK=32, 4 waves (each 64x64 = 4x4 frags of 16x16x32 bf16 MFMA)
template <typename CT>
__global__ __launch_bounds__(256) void gemm_bt(const u16* __restrict__ A,
                                               const u16* __restrict__ Bt,
                                               CT* __restrict__ C, int M, int N, int K) {
  __shared__ u16 As[128 * 32];
  __shared__ u16 Bs[128 * 32];
  const int tid = threadIdx.x;
  const int wave = tid >> 6, lane = tid & 63;
  const int g = lane >> 4, c16 = lane & 15;
  const int bm = blockIdx.y * 128, bn = blockIdx.x * 128;
  const int wr = (wave >> 1) * 64, wc = (wave & 1) * 64;
  f32x4 acc[4][4] = {};
  // staging: wave w covers rows [w*32, w*32+32) of each tile; 2 instrs x 16 rows
  // lane -> row +(lane>>2), bytes (lane&3)*16 within 64B row
  const int srow = wave * 32 + (lane >> 2);
  const int scol = (lane & 3) * 8;
  const u16* agp = A + (size_t)(bm + srow) * K + scol;
  const u16* bgp = Bt + (size_t)(bn + srow) * K + scol;
  u16* alp = As + (wave * 32) * 32;
  u16* blp = Bs + (wave * 32) * 32;
  for (int k0 = 0; k0 < K; k0 += 32) {
    gload_lds16(agp + k0, alp);
    gload_lds16(agp + k0 + (size_t)16 * K, alp + 16 * 32);
    gload_lds16(bgp + k0, blp);
    gload_lds16(bgp + k0 + (size_t)16 * K, blp + 16 * 32);
    __syncthreads();  // drains vmcnt before barrier (compiler-enforced)
    bf16x8 af[4], bfr[4];
#pragma unroll
    for (int i = 0; i < 4; ++i)
      af[i] = *(const bf16x8*)(As + (wr + i * 16 + c16) * 32 + g * 8);
#pragma unroll
    for (int j = 0; j < 4; ++j)
      bfr[j] = *(const bf16x8*)(Bs + (wc + j * 16 + c16) * 32 + g * 8);
#pragma unroll
    for (int i = 0; i < 4; ++i)
#pragma unroll
      for (int j = 0; j < 4; ++j)
        acc[i][j] = __builtin_amdgcn_mfma_f32_16x16x32_bf16(af[i], bfr[j], acc[i][j], 0, 0, 0);
    __syncthreads();
  }
  // C/D layout: row = g*4 + r, col = c16 (m89-verified)
#pragma unroll
  for (int i = 0; i < 4; ++i)
#pragma unroll
    for (int j = 0; j < 4; ++j)
#pragma unroll
      for (int r = 0; r < 4; ++r) {
        int row = bm + wr + i * 16 + g * 4 + r;
        int col = bn + wc + j * 16 + c16;
        float v = acc[i][j][r];
        if constexpr (sizeof(CT) == 2) C[(size_t)row * N + col] = f2bf(v);
        else                           C[(size_t)row * N + col] = v;
      }
}

// ---------------- K concat: past_k fp32 + Knew bf16 -> Kc bf16 [B,KH,S,128] ----------------
__global__ __launch_bounds__(256) void kcat(const float* __restrict__ past,
                                            const u16* __restrict__ knew,
                                            u16* __restrict__ out) {
  int idx = blockIdx.x * 256 + threadIdx.x;  // 655,360 exact: (b,kh,s,d8)
  int bkh = idx / 40960;
  int rem = idx - bkh * 40960;
  int s = rem >> 4;
  int d0 = (rem & 15) * 8;
  u16x8 o;
  if (s < 512) {
    const float4* s4 = (const float4*)(past + ((size_t)bkh * 512 + s) * 128 + d0);
    float4 a = s4[0], c = s4[1];
    o[0] = f2bf(a.x); o[1] = f2bf(a.y); o[2] = f2bf(a.z); o[3] = f2bf(a.w);
    o[4] = f2bf(c.x); o[5] = f2bf(c.y); o[6] = f2bf(c.z); o[7] = f2bf(c.w);
  } else {
    int b = bkh >> 3, khh = bkh & 7;
    o = *(const u16x8*)(knew + (size_t)(b * 2048 + s - 512) * 1024 + khh * 128 + d0);
  }
  *(u16x8*)(out + (size_t)idx * 8) = o;
}

// ------------- V concat + transpose: -> Vt bf16 [B,KH,128(d),2560(s)] -------------
__global__ __launch_bounds__(256) void vt_build(const float* __restrict__ past,
                                                const u16* __restrict__ vnew,
                                                u16* __restrict__ vt) {
  __shared__ float t[32][33];
  int tx = threadIdx.x & 31, ty = threadIdx.x >> 5;
  int s0 = blockIdx.x * 32, d0 = blockIdx.y * 32, bkh = blockIdx.z;
  int b = bkh >> 3, khh = bkh & 7;
#pragma unroll
  for (int i = 0; i < 4; ++i) {
    int s = s0 + ty + i * 8;
    float v;
    if (s < 512) v = past[((size_t)bkh * 512 + s) * 128 + d0 + tx];
    else         v = bf2f(vnew[(size_t)(b * 2048 + s - 512) * 1024 + khh * 128 + d0 + tx]);
    t[ty + i * 8][tx] = v;
  }
  __syncthreads();
#pragma unroll
  for (int i = 0; i < 4; ++i)
    vt[((size_t)bkh * 128 + d0 + ty + i * 8) * 2560 + s0 + tx] = f2bf(t[tx][ty + i * 8]);
}

// ---------------- flash attention fwd, causal with past offset P=512 ----------------
// block = (qt, h, b); 4 waves x 16 q-rows; KV tiles of 64 staged in LDS (XOR-swizzled).
// swapped QK^T: scT = mfma(K, Q) so softmax rows are lane-local (q = lane&15).
__global__ __launch_bounds__(256) void attn_fwd(const u16* __restrict__ Q,
                                                const u16* __restrict__ Kc,
                                                const u16* __restrict__ Vt,
                                                u16* __restrict__ Oa) {
  __shared__ u16 Ks[64 * 128];      // [s][d], 16B-blocks XOR-swizzled by (s&7)
  __shared__ u16 Vs[128 * 64];      // [d][s], 16B-blocks XOR-swizzled by (d&7)
  __shared__ u16 Ps[4][16 * 72];    // per-wave P round-trip, stride 72 kills conflicts
  const int tid = threadIdx.x;
  const int wave = tid >> 6, lane = tid & 63;
  const int g = lane >> 4, c16 = lane & 15;
  const int qt = blockIdx.x, h = blockIdx.y, b = blockIdx.z;
  const int kh = h >> 2;  // GQA: 4 q-heads per kv-head (repeat_interleave)
  const int q0 = qt * 64 + wave * 16;
  const float scale = 0.08838834764831845f;  // 1/sqrt(128)

  // Q fragments (B-operand): lane holds Q[q0+c16][kc*32 + g*8 + j]
  bf16x8 qf[4];
  const u16* qbase = Q + (size_t)(b * 2048 + q0 + c16) * 4096 + h * 128;
#pragma unroll
  for (int kc = 0; kc < 4; ++kc) qf[kc] = *(const bf16x8*)(qbase + kc * 32 + g * 8);

  float m_run = -1e30f, l_run = 0.f;  // softmax state for q = c16 (lane-owned)
  f32x4 oacc[8] = {};                 // oacc[dj][r] = out[q=g*4+r][d=dj*16+c16]
  const int ntiles = qt + 9;          // keys 0 .. P + qt*64 + 63; only last tile masked
  const u16* kbase = Kc + (size_t)(b * 8 + kh) * 2560 * 128;
  const u16* vbase = Vt + (size_t)(b * 8 + kh) * 128 * 2560;

  for (int t = 0; t < ntiles; ++t) {
    const int s0 = t * 64;
    // stage K tile [64][128]: 4 instrs/wave, linear LDS dest, inverse-swizzled source
#pragma unroll
    for (int i = 0; i < 4; ++i) {
      int r = wave * 16 + i * 4 + (lane >> 4);
      int bsrc = c16 ^ (r & 7);
      gload_lds16(kbase + (size_t)(s0 + r) * 128 + bsrc * 8, Ks + (wave * 16 + i * 4) * 128);
    }
    // stage Vt tile [128][64]
#pragma unroll
    for (int i = 0; i < 4; ++i) {
      int r = wave * 32 + i * 8 + (lane >> 3);
      int bsrc = (lane & 7) ^ (r & 7);
      gload_lds16(vbase + (size_t)r * 2560 + s0 + bsrc * 8, Vs + (wave * 32 + i * 8) * 64);
    }
    __syncthreads();

    // scT[s][q]: sc[sf][r] = scores^T[s = sf*16 + g*4 + r][q = c16]
    f32x4 sc[4] = {};
#pragma unroll
    for (int sf = 0; sf < 4; ++sf) {
      const int sr = sf * 16 + c16;
#pragma unroll
      for (int kc = 0; kc < 4; ++kc) {
        const int blk = (kc * 4 + g) ^ (sr & 7);
        bf16x8 kf = *(const bf16x8*)(Ks + sr * 128 + blk * 8);
        sc[sf] = __builtin_amdgcn_mfma_f32_16x16x32_bf16(kf, qf[kc], sc[sf], 0, 0, 0);
      }
    }

    const bool last = (t == ntiles - 1);
    float pm = -1e30f;
#pragma unroll
    for (int sf = 0; sf < 4; ++sf)
#pragma unroll
      for (int r = 0; r < 4; ++r) {
        float v = sc[sf][r] * scale;
        if (last) {  // diagonal tile: key s0+sidx allowed iff sidx <= wave*16 + q_local
          int sidx = sf * 16 + g * 4 + r;
          if (sidx > wave * 16 + c16) v = -1e30f;
        }
        sc[sf][r] = v;
        pm = fmaxf(pm, v);
      }
    pm = fmaxf(pm, __shfl_xor(pm, 16));
    pm = fmaxf(pm, __shfl_xor(pm, 32));
    const float m_new = fmaxf(m_run, pm);
    const float corr = __expf(m_run - m_new);
    float ls = 0.f;
#pragma unroll
    for (int sf = 0; sf < 4; ++sf) {
      float p0 = __expf(sc[sf][0] - m_new);
      float p1 = __expf(sc[sf][1] - m_new);
      float p2 = __expf(sc[sf][2] - m_new);
      float p3 = __expf(sc[sf][3] - m_new);
      ls += (p0 + p1) + (p2 + p3);
      u32 w0 = (u32)f2bf(p0) | ((u32)f2bf(p1) << 16);
      u32 w1 = (u32)f2bf(p2) | ((u32)f2bf(p3) << 16);
      *(u32*)&Ps[wave][c16 * 72 + sf * 16 + g * 4]     = w0;
      *(u32*)&Ps[wave][c16 * 72 + sf * 16 + g * 4 + 2] = w1;
    }
    ls += __shfl_xor(ls, 16);
    ls += __shfl_xor(ls, 32);
    l_run = l_run * corr + ls;
    m_run = m_new;

    // rescale O by per-row corr (rows of D-layout = g*4 + r, owner lane = that q)
#pragma unroll
    for (int r = 0; r < 4; ++r) {
      float cr = __shfl(corr, g * 4 + r, 64);
#pragma unroll
      for (int dj = 0; dj < 8; ++dj) oacc[dj][r] *= cr;
    }

    // PV: A = P[q=c16][s], B = V[s][d] from Vs (wave-local Ps, no barrier needed)
    bf16x8 pa0 = *(const bf16x8*)&Ps[wave][c16 * 72 + g * 8];
    bf16x8 pa1 = *(const bf16x8*)&Ps[wave][c16 * 72 + 32 + g * 8];
#pragma unroll
    for (int dj = 0; dj < 8; ++dj) {
      const int d = dj * 16 + c16;
      const int blk0 = g ^ (d & 7);
      const int blk1 = (4 + g) ^ (d & 7);
      bf16x8 v0 = *(const bf16x8*)(Vs + d * 64 + blk0 * 8);
      oacc[dj] = __builtin_amdgcn_mfma_f32_16x16x32_bf16(pa0, v0, oacc[dj], 0, 0, 0);
      bf16x8 v1 = *(const bf16x8*)(Vs + d * 64 + blk1 * 8);
      oacc[dj] = __builtin_amdgcn_mfma_f32_16x16x32_bf16(pa1, v1, oacc[dj], 0, 0, 0);
    }
    __syncthreads();
  }

#pragma unroll
  for (int r = 0; r < 4; ++r) {
    float inv = 1.f / __shfl(l_run, g * 4 + r, 64);
    u16* orow = Oa + (size_t)(b * 2048 + q0 + g * 4 + r) * 4096 + h * 128;
#pragma unroll
    for (int dj = 0; dj < 8; ++dj) orow[dj * 16 + c16] = f2bf(oacc[dj][r] * inv);
  }
}

extern "C" void kernel_launch(void* const* d_in, const int* in_sizes, int n_in,
                              void* d_out, int out_size, void* d_ws, size_t ws_size,
                              hipStream_t stream) {
  (void)in_sizes; (void)n_in; (void)out_size; (void)ws_size;
  const float* x  = (const float*)d_in[0];
  // d_in[1] = mask — causal-with-past structure implemented analytically
  const float* pk = (const float*)d_in[2];
  const float* pv = (const float*)d_in[3];
  const float* Wq = (const float*)d_in[4];
  const float* Wk = (const float*)d_in[5];
  const float* Wv = (const float*)d_in[6];
  const float* Wo = (const float*)d_in[7];
  float* out = (float*)d_out;

  char* w = (char*)d_ws;  // peak 138.4 MB, wt reused for all 4 weights; ao aliases xb
  u16* xb   = (u16*)(w);                 // 33,554,432 B  x bf16 [4096,4096]
  u16* wt   = (u16*)(w + 33554432);      // 33,554,432 B  transposed weight (reused)
  u16* qb   = (u16*)(w + 67108864);      // 33,554,432 B  Q bf16 [4096, 4096]
  u16* knew = (u16*)(w + 100663296);     //  8,388,608 B  K_new bf16 [4096, 1024]
  u16* vnew = (u16*)(w + 109051904);     //  8,388,608 B  V_new bf16 [4096, 1024]
  u16* kc   = (u16*)(w + 117440512);     // 10,485,760 B  Kc bf16 [2,8,2560,128]
  u16* vt   = (u16*)(w + 127926272);     // 10,485,760 B  Vt bf16 [2,8,128,2560]
  u16* ao   = xb;                        // attn out aliases xb (xb dead by then)

  cast_x_kernel<<<8192, 256, 0, stream>>>(x, xb);
  transpose_cast<<<dim3(128, 128), 256, 0, stream>>>(Wq, wt, 4096, 4096);
  gemm_bt<u16><<<dim3(32, 32), 256, 0, stream>>>(xb, wt, qb, 4096, 4096, 4096);
  transpose_cast<<<dim3(32, 128), 256, 0, stream>>>(Wk, wt, 4096, 1024);
  gemm_bt<u16><<<dim3(8, 32), 256, 0, stream>>>(xb, wt, knew, 4096, 1024, 4096);
  transpose_cast<<<dim3(32, 128), 256, 0, stream>>>(Wv, wt, 4096, 1024);
  gemm_bt<u16><<<dim3(8, 32), 256, 0, stream>>>(xb, wt, vnew, 4096, 1024, 4096);
  kcat<<<2560, 256, 0, stream>>>(pk, knew, kc);
  vt_build<<<dim3(80, 4, 16), 256, 0, stream>>>(pv, vnew, vt);
  attn_fwd<<<dim3(32, 32, 2), 256, 0, stream>>>(qb, kc, vt, ao);
  transpose_cast<<<dim3(128, 128), 256, 0, stream>>>(Wo, wt, 4096, 4096);
  gemm_bt<float><<<dim3(32, 32), 256, 0, stream>>>(ao, wt, out, 4096, 4096, 4096);
}

// Round 3
// 948.093 us; speedup vs baseline: 1.1851x; 1.1851x over previous
//
#include <hip/hip_runtime.h>

using u16 = unsigned short;
using u32 = unsigned int;
using bf16x8 = __attribute__((ext_vector_type(8))) __bf16;
using f32x4  = __attribute__((ext_vector_type(4))) float;
using f32x16 = __attribute__((ext_vector_type(16))) float;
using u16x8  = __attribute__((ext_vector_type(8))) u16;
using u32x2  = __attribute__((ext_vector_type(2))) u32;

#define DEV static __device__ __forceinline__

DEV float bf2f(u16 u) { union { u32 i; float f; } c; c.i = ((u32)u) << 16; return c.f; }
DEV u16 f2bf(float f) {
  union { float f; u32 i; } c; c.f = f;
  u32 r = c.i + 0x7FFFu + ((c.i >> 16) & 1u);
  return (u16)(r >> 16);
}

// async global->LDS, 16B per lane; lds dest must be wave-uniform base (HW adds lane*16)
DEV void gload_lds16(const void* g, void* l) {
  __builtin_amdgcn_global_load_lds(
      (const __attribute__((address_space(1))) u32*)g,
      (__attribute__((address_space(3))) u32*)l, 16, 0, 0);
}

// v_cvt_pk_bf16_f32: pack 2 f32 -> 2 bf16 in one u32 (lo = src0), RNE
DEV u32 cvtpk(float lo, float hi) {
  u32 r;
  asm("v_cvt_pk_bf16_f32 %0, %1, %2" : "=v"(r) : "v"(lo), "v"(hi));
  return r;
}

// v_permlane32_swap: a' = {a.lo | b.lo_from_partner}, b' = {a.hi_from_partner | b.hi}
DEV void plswap(u32& a, u32& b) {
  auto r = __builtin_amdgcn_permlane32_swap((int)a, (int)b, false, false);
  a = (u32)r[0]; b = (u32)r[1];
}
DEV float crossmax(float x) {
  union { float f; u32 i; } c; c.f = x;
  u32 a = c.i, b = c.i;
  plswap(a, b);
  union { u32 i; float f; } A, B; A.i = a; B.i = b;
  return fmaxf(A.f, B.f);
}
DEV float crosssum(float x) {
  union { float f; u32 i; } c; c.f = x;
  u32 a = c.i, b = c.i;
  plswap(a, b);
  union { u32 i; float f; } A, B; A.i = a; B.i = b;
  return A.f + B.f;
}

// ---------------- cast x: fp32 -> bf16, 8 elems/thread ----------------
__global__ __launch_bounds__(256) void cast_x_kernel(const float* __restrict__ x,
                                                     u16* __restrict__ xb) {
  size_t i = (size_t)blockIdx.x * 256 + threadIdx.x;  // 2,097,152 threads exact
  const float4* s4 = (const float4*)(x + i * 8);
  float4 a = s4[0], c = s4[1];
  u16x8 o;
  o[0] = f2bf(a.x); o[1] = f2bf(a.y); o[2] = f2bf(a.z); o[3] = f2bf(a.w);
  o[4] = f2bf(c.x); o[5] = f2bf(c.y); o[6] = f2bf(c.z); o[7] = f2bf(c.w);
  *(u16x8*)(xb + i * 8) = o;
}

// ------------- W [K,N] fp32 -> Wt [N,K] bf16, tiled LDS transpose -------------
__global__ __launch_bounds__(256) void transpose_cast(const float* __restrict__ W,
                                                      u16* __restrict__ Wt, int K, int N) {
  __shared__ float t[32][33];
  int tx = threadIdx.x & 31, ty = threadIdx.x >> 5;
  int n0 = blockIdx.x * 32, k0 = blockIdx.y * 32;
#pragma unroll
  for (int i = 0; i < 4; ++i)
    t[ty + i * 8][tx] = W[(size_t)(k0 + ty + i * 8) * N + n0 + tx];
  __syncthreads();
#pragma unroll
  for (int i = 0; i < 4; ++i)
    Wt[(size_t)(n0 + ty + i * 8) * K + k0 + tx] = f2bf(t[tx][ty + i * 8]);
}

// ---------------- GEMM: C[M,N] = A[M,K] * Bt[N,K]^T (m97 structure) ----------------
template <typename CT>
__global__ __launch_bounds__(256) void gemm_bt(const u16* __restrict__ A,
                                               const u16* __restrict__ Bt,
                                               CT* __restrict__ C, int M, int N, int K) {
  __shared__ u16 As[128 * 32];
  __shared__ u16 Bs[128 * 32];
  const int tid = threadIdx.x;
  const int wave = tid >> 6, lane = tid & 63;
  const int g = lane >> 4, c16 = lane & 15;
  const int bm = blockIdx.y * 128, bn = blockIdx.x * 128;
  const int wr = (wave >> 1) * 64, wc = (wave & 1) * 64;
  f32x4 acc[4][4] = {};
  const int srow = wave * 32 + (lane >> 2);
  const int scol = (lane & 3) * 8;
  const u16* agp = A + (size_t)(bm + srow) * K + scol;
  const u16* bgp = Bt + (size_t)(bn + srow) * K + scol;
  u16* alp = As + (wave * 32) * 32;
  u16* blp = Bs + (wave * 32) * 32;
  for (int k0 = 0; k0 < K; k0 += 32) {
    gload_lds16(agp + k0, alp);
    gload_lds16(agp + k0 + (size_t)16 * K, alp + 16 * 32);
    gload_lds16(bgp + k0, blp);
    gload_lds16(bgp + k0 + (size_t)16 * K, blp + 16 * 32);
    __syncthreads();
    bf16x8 af[4], bfr[4];
#pragma unroll
    for (int i = 0; i < 4; ++i)
      af[i] = *(const bf16x8*)(As + (wr + i * 16 + c16) * 32 + g * 8);
#pragma unroll
    for (int j = 0; j < 4; ++j)
      bfr[j] = *(const bf16x8*)(Bs + (wc + j * 16 + c16) * 32 + g * 8);
#pragma unroll
    for (int i = 0; i < 4; ++i)
#pragma unroll
      for (int j = 0; j < 4; ++j)
        acc[i][j] = __builtin_amdgcn_mfma_f32_16x16x32_bf16(af[i], bfr[j], acc[i][j], 0, 0, 0);
    __syncthreads();
  }
#pragma unroll
  for (int i = 0; i < 4; ++i)
#pragma unroll
    for (int j = 0; j < 4; ++j)
#pragma unroll
      for (int r = 0; r < 4; ++r) {
        int row = bm + wr + i * 16 + g * 4 + r;
        int col = bn + wc + j * 16 + c16;
        float v = acc[i][j][r];
        if constexpr (sizeof(CT) == 2) C[(size_t)row * N + col] = f2bf(v);
        else                           C[(size_t)row * N + col] = v;
      }
}

// ---- K concat: past_k fp32 + kvb(K cols) bf16 -> Kc bf16 [B,KH,S,128] ----
__global__ __launch_bounds__(256) void kcat(const float* __restrict__ past,
                                            const u16* __restrict__ kvb,
                                            u16* __restrict__ out) {
  int idx = blockIdx.x * 256 + threadIdx.x;  // 655,360 exact: (b,kh,s,d8)
  int bkh = idx / 40960;
  int rem = idx - bkh * 40960;
  int s = rem >> 4;
  int d0 = (rem & 15) * 8;
  u16x8 o;
  if (s < 512) {
    const float4* s4 = (const float4*)(past + ((size_t)bkh * 512 + s) * 128 + d0);
    float4 a = s4[0], c = s4[1];
    o[0] = f2bf(a.x); o[1] = f2bf(a.y); o[2] = f2bf(a.z); o[3] = f2bf(a.w);
    o[4] = f2bf(c.x); o[5] = f2bf(c.y); o[6] = f2bf(c.z); o[7] = f2bf(c.w);
  } else {
    int b = bkh >> 3, khh = bkh & 7;
    o = *(const u16x8*)(kvb + (size_t)(b * 2048 + s - 512) * 2048 + khh * 128 + d0);
  }
  *(u16x8*)(out + (size_t)idx * 8) = o;
}

// ---- V concat + transpose: past_v fp32 + kvb(V cols) -> Vt bf16 [B,KH,128,2560] ----
__global__ __launch_bounds__(256) void vt_build(const float* __restrict__ past,
                                                const u16* __restrict__ kvb,
                                                u16* __restrict__ vt) {
  __shared__ float t[32][33];
  int tx = threadIdx.x & 31, ty = threadIdx.x >> 5;
  int s0 = blockIdx.x * 32, d0 = blockIdx.y * 32, bkh = blockIdx.z;
  int b = bkh >> 3, khh = bkh & 7;
#pragma unroll
  for (int i = 0; i < 4; ++i) {
    int s = s0 + ty + i * 8;
    float v;
    if (s < 512) v = past[((size_t)bkh * 512 + s) * 128 + d0 + tx];
    else         v = bf2f(kvb[(size_t)(b * 2048 + s - 512) * 2048 + 1024 + khh * 128 + d0 + tx]);
    t[ty + i * 8][tx] = v;
  }
  __syncthreads();
#pragma unroll
  for (int i = 0; i < 4; ++i)
    vt[((size_t)bkh * 128 + d0 + ty + i * 8) * 2560 + s0 + tx] = f2bf(t[tx][ty + i * 8]);
}

// ---------------- flash attention fwd: 8 waves x 32 q, 32x32x16 MFMA ----------------
// Double-swapped: scT = mfma(K, Q)  (col = q, lane-local softmax rows)
//                 O^T = mfma(V^T, P) (col = q, lane-local rescale/normalize)
// K/V double-buffered in LDS (XOR-swizzled via pre-swizzled global src), counted vmcnt.
__global__ __launch_bounds__(512, 2) void attn_fwd(const u16* __restrict__ Q,
                                                   const u16* __restrict__ Kc,
                                                   const u16* __restrict__ Vt,
                                                   u16* __restrict__ Oa) {
  __shared__ u16 lds[2][16384];  // [buf][ Ks 64x128 | Vs 128x64 ]
  const int tid = threadIdx.x;
  const int w = tid >> 6, lane = tid & 63;
  const int c32 = lane & 31, hi = lane >> 5;
  const int qt = blockIdx.x, h = blockIdx.y, b = blockIdx.z;
  const int kh = h >> 2;               // GQA repeat_interleave, g=4
  const int q0 = qt * 256;
  const int qw = q0 + w * 32;          // wave's q base
  const int qg = qw + c32;             // lane's q (within L)
  const float SCALE = 0.08838834764831845f;  // 1/sqrt(128)

  // Q fragments (B-operand): lane holds Q[k = kc*16 + hi*8 + j][q = qg]
  bf16x8 qf[8];
  const u16* qbase = Q + (size_t)(b * 2048 + qg) * 4096 + h * 128 + hi * 8;
#pragma unroll
  for (int kc = 0; kc < 8; ++kc) qf[kc] = *(const bf16x8*)(qbase + kc * 16);

  // staging offsets (pre-swizzled global source, linear LDS dest)
  const int krow = w * 4 + (lane >> 4);                       // 0..31
  const int koff = krow * 128 + (((lane & 15) ^ (krow & 7)) * 8);
  const int vrow = w * 8 + (lane >> 3);                       // 0..63
  const int voff = vrow * 2560 + (((lane & 7) ^ (vrow & 7)) * 8);
  const u16* kp = Kc + (size_t)(b * 8 + kh) * 2560 * 128;
  const u16* vp = Vt + (size_t)(b * 8 + kh) * 128 * 2560;
  u16* ksd0 = &lds[0][w * 512]; u16* ksd1 = &lds[1][w * 512];
  u16* vsd0 = &lds[0][8192 + w * 512]; u16* vsd1 = &lds[1][8192 + w * 512];

  const int ntiles = 4 * qt + 12;

  // prologue: stage tile 0 -> buf 0
  gload_lds16(kp + koff, ksd0);
  gload_lds16(kp + koff + 4096, ksd0 + 4096);
  gload_lds16(vp + voff, vsd0);
  gload_lds16(vp + voff + 163840, vsd0 + 4096);

  float m_run = -1e30f, l_run = 0.f;
  f32x16 oacc[4] = {};
  const int s7 = c32 & 7;

  for (int t = 0; t < ntiles; ++t) {
    const int pb = t & 1;
    if (t + 1 < ntiles) {
      u16* kd = pb ? ksd0 : ksd1;
      u16* vd = pb ? vsd0 : vsd1;
      gload_lds16(kp + 8192 + koff, kd);
      gload_lds16(kp + 8192 + koff + 4096, kd + 4096);
      gload_lds16(vp + 64 + voff, vd);
      gload_lds16(vp + 64 + voff + 163840, vd + 4096);
      asm volatile("s_waitcnt vmcnt(4)" ::: "memory");
    } else {
      asm volatile("s_waitcnt vmcnt(0)" ::: "memory");
    }
    __builtin_amdgcn_s_barrier();

    const int dd = 512 + qw - t * 64;  // per-wave mask margin
    if (dd >= -31) {                   // not fully masked for this wave
      const u16* Ks = &lds[pb][0];
      const u16* Vs = &lds[pb][8192];

      // QK^T: sc[sb][r] = scores[s = t*64 + sb*32 + (r&3)+8*(r>>2)+4*hi][q = qg]
      f32x16 sc[2] = {};
#pragma unroll
      for (int kc = 0; kc < 8; ++kc) {
#pragma unroll
        for (int sb = 0; sb < 2; ++sb) {
          const int sr = sb * 32 + c32;
          bf16x8 kf = *(const bf16x8*)(Ks + sr * 128 + (((kc * 2 + hi) ^ s7) * 8));
          sc[sb] = __builtin_amdgcn_mfma_f32_32x32x16_bf16(kf, qf[kc], sc[sb], 0, 0, 0);
        }
      }

      // causal mask (raw domain); only near-diagonal tiles need it
      if (dd < 63) {
        const int base = 4 * hi - c32;
#pragma unroll
        for (int sb = 0; sb < 2; ++sb)
#pragma unroll
          for (int r = 0; r < 16; ++r) {
            const int srow = sb * 32 + (r & 3) + 8 * (r >> 2);
            if (srow + base > dd) sc[sb][r] = -1e30f;
          }
      }

      // row max (lane-local + cross-half)
      float pmax = -1e30f;
#pragma unroll
      for (int sb = 0; sb < 2; ++sb)
#pragma unroll
        for (int r = 0; r < 16; ++r) pmax = fmaxf(pmax, sc[sb][r]);
      pmax = crossmax(pmax);

      // defer-max rescale (raw threshold 64 ~ exp(5.7) bound on P)
      if (__any(pmax > m_run + 64.f)) {
        const float mn = fmaxf(m_run, pmax);
        const float corr = __expf((m_run - mn) * SCALE);
#pragma unroll
        for (int db = 0; db < 4; ++db)
#pragma unroll
          for (int r = 0; r < 16; ++r) oacc[db][r] *= corr;
        l_run *= corr;
        m_run = mn;
      }

      // P = exp((sc - m) * scale), in place; row sum
      const float nms = -m_run * SCALE;
      float ls = 0.f;
#pragma unroll
      for (int sb = 0; sb < 2; ++sb)
#pragma unroll
        for (int r = 0; r < 16; ++r) {
          float p = __expf(fmaf(sc[sb][r], SCALE, nms));
          sc[sb][r] = p;
          ls += p;
        }
      l_run += crosssum(ls);

      // build PV B-fragments in-register: pa[c] covers s-chunk c*16..+15
      bf16x8 pa[4];
#pragma unroll
      for (int c = 0; c < 4; ++c) {
        const int sb = c >> 1, bb = (c & 1) * 8;
        u32 a  = cvtpk(sc[sb][bb + 0], sc[sb][bb + 1]);
        u32 b2 = cvtpk(sc[sb][bb + 2], sc[sb][bb + 3]);
        u32 c2 = cvtpk(sc[sb][bb + 4], sc[sb][bb + 5]);
        u32 d2 = cvtpk(sc[sb][bb + 6], sc[sb][bb + 7]);
        plswap(a, c2);   // a -> w0, c2 -> w2
        plswap(b2, d2);  // b2 -> w1, d2 -> w3
        union { u32 u[4]; bf16x8 v; } cv;
        cv.u[0] = a; cv.u[1] = b2; cv.u[2] = c2; cv.u[3] = d2;
        pa[c] = cv.v;
      }

      // PV: oacc[db] (O^T block rows d = db*32+..., col q) += V^T chunk * P chunk
#pragma unroll
      for (int c = 0; c < 4; ++c) {
#pragma unroll
        for (int db = 0; db < 4; ++db) {
          const int d = db * 32 + c32;
          bf16x8 vf = *(const bf16x8*)(Vs + d * 64 + (((c * 2 + hi) ^ s7) * 8));
          oacc[db] = __builtin_amdgcn_mfma_f32_32x32x16_bf16(vf, pa[c], oacc[db], 0, 0, 0);
        }
      }
    }
    __builtin_amdgcn_s_barrier();
    kp += 8192; vp += 64;
  }

  // epilogue: O^T rows d = db*32 + (r&3) + 8*(r>>2) + 4*hi, col q = qg (lane-local l)
  const float linv = 1.f / l_run;
  u16* ob = Oa + (size_t)(b * 2048 + qg) * 4096 + h * 128 + 4 * hi;
#pragma unroll
  for (int db = 0; db < 4; ++db)
#pragma unroll
    for (int rg = 0; rg < 4; ++rg) {
      u32x2 st;
      st[0] = cvtpk(oacc[db][rg * 4 + 0] * linv, oacc[db][rg * 4 + 1] * linv);
      st[1] = cvtpk(oacc[db][rg * 4 + 2] * linv, oacc[db][rg * 4 + 3] * linv);
      *(u32x2*)(ob + db * 32 + rg * 8) = st;
    }
}

extern "C" void kernel_launch(void* const* d_in, const int* in_sizes, int n_in,
                              void* d_out, int out_size, void* d_ws, size_t ws_size,
                              hipStream_t stream) {
  (void)in_sizes; (void)n_in; (void)out_size; (void)ws_size;
  const float* x  = (const float*)d_in[0];
  // d_in[1] = mask — causal-with-past structure implemented analytically
  const float* pk = (const float*)d_in[2];
  const float* pv = (const float*)d_in[3];
  const float* Wq = (const float*)d_in[4];
  const float* Wk = (const float*)d_in[5];
  const float* Wv = (const float*)d_in[6];
  const float* Wo = (const float*)d_in[7];
  float* out = (float*)d_out;

  char* w = (char*)d_ws;  // peak 132 MB
  u16* xb  = (u16*)(w);                  // [0,32M)   x bf16 [4096,4096]; ao aliases later
  u16* wt  = (u16*)(w + 33554432);       // [32M,64M) Wq^T 32MB / Wk^T+Wv^T 16MB / Wo^T 32MB
  u16* qb  = (u16*)(w + 67108864);       // [64M,96M) Q bf16 [4096,4096]
  u16* kvb = (u16*)(w + 100663296);      // [96M,112M) KV bf16 [4096,2048] (K:0-1023, V:1024-2047)
  u16* kc  = (u16*)(w + 117440512);      // [112M,122M) Kc bf16 [2,8,2560,128]
  u16* vt  = (u16*)(w + 127926272);      // [122M,132M) Vt bf16 [2,8,128,2560]
  u16* ao  = xb;                         // attn out aliases xb (xb dead after KV GEMM)

  cast_x_kernel<<<8192, 256, 0, stream>>>(x, xb);
  transpose_cast<<<dim3(128, 128), 256, 0, stream>>>(Wq, wt, 4096, 4096);
  gemm_bt<u16><<<dim3(32, 32), 256, 0, stream>>>(xb, wt, qb, 4096, 4096, 4096);
  transpose_cast<<<dim3(32, 128), 256, 0, stream>>>(Wk, wt, 4096, 1024);
  transpose_cast<<<dim3(32, 128), 256, 0, stream>>>(Wv, wt + (size_t)1024 * 4096, 4096, 1024);
  gemm_bt<u16><<<dim3(16, 32), 256, 0, stream>>>(xb, wt, kvb, 4096, 2048, 4096);
  kcat<<<2560, 256, 0, stream>>>(pk, kvb, kc);
  vt_build<<<dim3(80, 4, 16), 256, 0, stream>>>(pv, kvb, vt);
  transpose_cast<<<dim3(128, 128), 256, 0, stream>>>(Wo, wt, 4096, 4096);
  attn_fwd<<<dim3(8, 32, 2), 512, 0, stream>>>(qb, kc, vt, ao);
  gemm_bt<float><<<dim3(32, 32), 256, 0, stream>>>(ao, wt, out, 4096, 4096, 4096);
}

// Round 4
// 830.487 us; speedup vs baseline: 1.3529x; 1.1416x over previous
//
#include <hip/hip_runtime.h>

using u16 = unsigned short;
using u32 = unsigned int;
using bf16x8 = __attribute__((ext_vector_type(8))) __bf16;
using f32x4  = __attribute__((ext_vector_type(4))) float;
using f32x16 = __attribute__((ext_vector_type(16))) float;
using u16x8  = __attribute__((ext_vector_type(8))) u16;
using u32x2  = __attribute__((ext_vector_type(2))) u32;

#define DEV static __device__ __forceinline__

DEV float bf2f(u16 u) { union { u32 i; float f; } c; c.i = ((u32)u) << 16; return c.f; }
DEV u16 f2bf(float f) {
  union { float f; u32 i; } c; c.f = f;
  u32 r = c.i + 0x7FFFu + ((c.i >> 16) & 1u);
  return (u16)(r >> 16);
}

// async global->LDS, 16B per lane; lds dest must be wave-uniform base (HW adds lane*16)
DEV void gload_lds16(const void* g, void* l) {
  __builtin_amdgcn_global_load_lds(
      (const __attribute__((address_space(1))) u32*)g,
      (__attribute__((address_space(3))) u32*)l, 16, 0, 0);
}

DEV u32 cvtpk(float lo, float hi) {
  u32 r;
  asm("v_cvt_pk_bf16_f32 %0, %1, %2" : "=v"(r) : "v"(lo), "v"(hi));
  return r;
}
DEV void plswap(u32& a, u32& b) {
  auto r = __builtin_amdgcn_permlane32_swap((int)a, (int)b, false, false);
  a = (u32)r[0]; b = (u32)r[1];
}
DEV float crossmax(float x) {
  union { float f; u32 i; } c; c.f = x;
  u32 a = c.i, b = c.i;
  plswap(a, b);
  union { u32 i; float f; } A, B; A.i = a; B.i = b;
  return fmaxf(A.f, B.f);
}
DEV float crosssum(float x) {
  union { float f; u32 i; } c; c.f = x;
  u32 a = c.i, b = c.i;
  plswap(a, b);
  union { u32 i; float f; } A, B; A.i = a; B.i = b;
  return A.f + B.f;
}

DEV void fence_barrier() {
  asm volatile("" ::: "memory");
  __builtin_amdgcn_s_barrier();
  asm volatile("" ::: "memory");
}

// ---------------- cast x: fp32 -> bf16, 8 elems/thread ----------------
__global__ __launch_bounds__(256) void cast_x_kernel(const float* __restrict__ x,
                                                     u16* __restrict__ xb) {
  size_t i = (size_t)blockIdx.x * 256 + threadIdx.x;
  const float4* s4 = (const float4*)(x + i * 8);
  float4 a = s4[0], c = s4[1];
  u16x8 o;
  o[0] = f2bf(a.x); o[1] = f2bf(a.y); o[2] = f2bf(a.z); o[3] = f2bf(a.w);
  o[4] = f2bf(c.x); o[5] = f2bf(c.y); o[6] = f2bf(c.z); o[7] = f2bf(c.w);
  *(u16x8*)(xb + i * 8) = o;
}

// ------------- W [K,N] fp32 -> Wt [N,K] bf16, tiled LDS transpose -------------
__global__ __launch_bounds__(256) void transpose_cast(const float* __restrict__ W,
                                                      u16* __restrict__ Wt, int K, int N) {
  __shared__ float t[32][33];
  int tx = threadIdx.x & 31, ty = threadIdx.x >> 5;
  int n0 = blockIdx.x * 32, k0 = blockIdx.y * 32;
#pragma unroll
  for (int i = 0; i < 4; ++i)
    t[ty + i * 8][tx] = W[(size_t)(k0 + ty + i * 8) * N + n0 + tx];
  __syncthreads();
#pragma unroll
  for (int i = 0; i < 4; ++i)
    Wt[(size_t)(n0 + ty + i * 8) * K + k0 + tx] = f2bf(t[tx][ty + i * 8]);
}

// ============ 256x256 8-phase GEMM: C[M,N] = A[M,K] * Bt[N,K]^T ============
// 8 waves (2M x 4N), per-wave 128x64 out, BK=64, 2 K-tiles per iteration.
// LDS 128 KiB: [buf][A 256p x 64k | B 256p x 64k], physical index p groups the
// quadrant-phase staging halves: A: p = swap67(row); B: p = colmap(col).
// XOR-swizzle (T2): LDS[p][kb] holds global k-block kb ^ (p&7) (both sides).
// vmcnt(4) only at phases 4 and 8 (T4); setprio around MFMA clusters (T5).

DEV int swap67(int p) { return (p & 63) | ((p & 64) << 1) | ((p & 128) >> 1); }
DEV int colmap(int p) { return (p & 31) | ((p & 96) << 1) | ((p >> 2) & 32); }

template <int PAR, int MH, int NH, bool VM, typename F>
DEV void gphase(const u16* lds, int wrp, int wcp, int c16, int g, int s7,
                f32x4 (&acc)[8][4], F&& stage) {
  bf16x8 af[4][2];
  bf16x8 bv[2][2];
#pragma unroll
  for (int fi = 0; fi < 4; ++fi) {
    const u16* rp = lds + PAR * 32768 + (MH * 128 + wrp + fi * 16 + c16) * 64;
    af[fi][0] = *(const bf16x8*)(rp + ((0 + g) ^ s7) * 8);
    af[fi][1] = *(const bf16x8*)(rp + ((4 + g) ^ s7) * 8);
  }
#pragma unroll
  for (int fj = 0; fj < 2; ++fj) {
    const u16* rp = lds + PAR * 32768 + 16384 + (NH * 128 + wcp + fj * 16 + c16) * 64;
    bv[fj][0] = *(const bf16x8*)(rp + ((0 + g) ^ s7) * 8);
    bv[fj][1] = *(const bf16x8*)(rp + ((4 + g) ^ s7) * 8);
  }
  stage();
  if (VM) asm volatile("s_waitcnt vmcnt(4)" ::: "memory");
  fence_barrier();
  __builtin_amdgcn_s_setprio(1);
#pragma unroll
  for (int fi = 0; fi < 4; ++fi)
#pragma unroll
    for (int fj = 0; fj < 2; ++fj) {
      acc[MH * 4 + fi][NH * 2 + fj] = __builtin_amdgcn_mfma_f32_16x16x32_bf16(
          af[fi][0], bv[fj][0], acc[MH * 4 + fi][NH * 2 + fj], 0, 0, 0);
      acc[MH * 4 + fi][NH * 2 + fj] = __builtin_amdgcn_mfma_f32_16x16x32_bf16(
          af[fi][1], bv[fj][1], acc[MH * 4 + fi][NH * 2 + fj], 0, 0, 0);
    }
  __builtin_amdgcn_s_setprio(0);
  fence_barrier();
}

template <typename CT>
__global__ __launch_bounds__(512, 2) void gemm8(const u16* __restrict__ A,
                                                const u16* __restrict__ Bt,
                                                CT* __restrict__ C, int M, int N, int K) {
  __shared__ u16 lds[65536];  // 128 KiB
  const int tid = threadIdx.x;
  const int w = tid >> 6, lane = tid & 63;
  const int g = lane >> 4, c16 = lane & 15, s7 = c16 & 7;
  // bijective XCD swizzle (nwg % 8 == 0 for all grids used)
  const int nwg = gridDim.x * gridDim.y;
  const int bid0 = blockIdx.y * gridDim.x + blockIdx.x;
  const int sb = (bid0 & 7) * (nwg >> 3) + (bid0 >> 3);
  const int bn = (sb % gridDim.x) * 256;
  const int bm = (sb / gridDim.x) * 256;
  const int wr = (w >> 2) * 128, wc = (w & 3) * 64;   // wave's C offsets
  const int wrp = (w >> 2) * 64, wcp = (w & 3) * 32;  // physical LDS bases

  // staging source offsets (u32, elements) and LDS dest offsets (u16 units)
  const int lr = lane >> 3;
  const int swz = ((lane & 7) ^ lr) * 8;  // pre-swizzled k-block (involution)
  u32 aOff[2][2], bOff[2][2];
#pragma unroll
  for (int h = 0; h < 2; ++h)
#pragma unroll
    for (int j = 0; j < 2; ++j) {
      int pb = h * 128 + (w * 2 + j) * 8;
      aOff[h][j] = (u32)(bm + swap67(pb) + lr) * (u32)K + swz;
      bOff[h][j] = (u32)(bn + colmap(pb) + lr) * (u32)K + swz;
    }
  auto stA = [&](int par, int h, int j, int ko) {
    gload_lds16(A + aOff[h][j] + ko, (u16*)lds + par * 32768 + h * 8192 + (w * 2 + j) * 512);
  };
  auto stB = [&](int par, int h, int j, int ko) {
    gload_lds16(Bt + bOff[h][j] + ko,
                (u16*)lds + par * 32768 + 16384 + h * 8192 + (w * 2 + j) * 512);
  };

  f32x4 acc[8][4] = {};

  // prologue: tile0 (all 4 halves) -> buf0; tile1 (AH0,BH0) -> buf1
  stA(0, 0, 0, 0); stA(0, 0, 1, 0); stB(0, 0, 0, 0); stB(0, 0, 1, 0);
  stA(0, 1, 0, 0); stA(0, 1, 1, 0); stB(0, 1, 0, 0); stB(0, 1, 1, 0);
  stA(1, 0, 0, 64); stA(1, 0, 1, 64); stB(1, 0, 0, 64); stB(1, 0, 1, 64);
  asm volatile("s_waitcnt vmcnt(4)" ::: "memory");
  fence_barrier();

  for (int kb = 64; kb < K; kb += 128) {  // kb = k-offset of tile b = odd tile
    const int kc = kb + 64, kd = kb + 128;
    const bool hc = kc < K, hd = kd < K;
    // ph1: Q(0,0) buf0 | stage AH1(b)+BH1(b) -> buf1
    gphase<0, 0, 0, false>(lds, wrp, wcp, c16, g, s7, acc, [&] {
      stA(1, 1, 0, kb); stA(1, 1, 1, kb); stB(1, 1, 0, kb); stB(1, 1, 1, kb);
    });
    // ph2: Q(0,1) buf0
    gphase<0, 0, 1, false>(lds, wrp, wcp, c16, g, s7, acc, [&] {});
    // ph3: Q(1,0) buf0 | stage AH0(c) -> buf0
    gphase<0, 1, 0, false>(lds, wrp, wcp, c16, g, s7, acc, [&] {
      if (hc) { stA(0, 0, 0, kc); stA(0, 0, 1, kc); }
    });
    // ph4: Q(1,1) buf0 | stage BH0(c); vmcnt(4)
    gphase<0, 1, 1, true>(lds, wrp, wcp, c16, g, s7, acc, [&] {
      if (hc) { stB(0, 0, 0, kc); stB(0, 0, 1, kc); }
    });
    // ph5: Q(0,0) buf1 | stage AH1(c)+BH1(c) -> buf0
    gphase<1, 0, 0, false>(lds, wrp, wcp, c16, g, s7, acc, [&] {
      if (hc) { stA(0, 1, 0, kc); stA(0, 1, 1, kc); stB(0, 1, 0, kc); stB(0, 1, 1, kc); }
    });
    // ph6: Q(0,1) buf1
    gphase<1, 0, 1, false>(lds, wrp, wcp, c16, g, s7, acc, [&] {});
    // ph7: Q(1,0) buf1 | stage AH0(d) -> buf1
    gphase<1, 1, 0, false>(lds, wrp, wcp, c16, g, s7, acc, [&] {
      if (hd) { stA(1, 0, 0, kd); stA(1, 0, 1, kd); }
    });
    // ph8: Q(1,1) buf1 | stage BH0(d); vmcnt(4)
    gphase<1, 1, 1, true>(lds, wrp, wcp, c16, g, s7, acc, [&] {
      if (hd) { stB(1, 0, 0, kd); stB(1, 0, 1, kd); }
    });
  }

  // epilogue: D-layout row = g*4+r, col = c16 per 16x16 frag
#pragma unroll
  for (int mf = 0; mf < 8; ++mf)
#pragma unroll
    for (int nf = 0; nf < 4; ++nf)
#pragma unroll
      for (int r = 0; r < 4; ++r) {
        int row = bm + wr + (mf >> 2) * 64 + (mf & 3) * 16 + g * 4 + r;
        int col = bn + wc + (nf >> 1) * 32 + (nf & 1) * 16 + c16;
        float v = acc[mf][nf][r];
        if constexpr (sizeof(CT) == 2) C[(size_t)row * N + col] = f2bf(v);
        else                           C[(size_t)row * N + col] = v;
      }
}

// ---- K concat: past_k fp32 + kvb(K cols) bf16 -> Kc bf16 [B,KH,S,128] ----
__global__ __launch_bounds__(256) void kcat(const float* __restrict__ past,
                                            const u16* __restrict__ kvb,
                                            u16* __restrict__ out) {
  int idx = blockIdx.x * 256 + threadIdx.x;  // (b,kh,s,d8)
  int bkh = idx / 40960;
  int rem = idx - bkh * 40960;
  int s = rem >> 4;
  int d0 = (rem & 15) * 8;
  u16x8 o;
  if (s < 512) {
    const float4* s4 = (const float4*)(past + ((size_t)bkh * 512 + s) * 128 + d0);
    float4 a = s4[0], c = s4[1];
    o[0] = f2bf(a.x); o[1] = f2bf(a.y); o[2] = f2bf(a.z); o[3] = f2bf(a.w);
    o[4] = f2bf(c.x); o[5] = f2bf(c.y); o[6] = f2bf(c.z); o[7] = f2bf(c.w);
  } else {
    int b = bkh >> 3, khh = bkh & 7;
    o = *(const u16x8*)(kvb + (size_t)(b * 2048 + s - 512) * 2048 + khh * 128 + d0);
  }
  *(u16x8*)(out + (size_t)idx * 8) = o;
}

// ---- V concat + transpose: -> Vt bf16 [B,KH,128,2560] ----
__global__ __launch_bounds__(256) void vt_build(const float* __restrict__ past,
                                                const u16* __restrict__ kvb,
                                                u16* __restrict__ vt) {
  __shared__ float t[32][33];
  int tx = threadIdx.x & 31, ty = threadIdx.x >> 5;
  int s0 = blockIdx.x * 32, d0 = blockIdx.y * 32, bkh = blockIdx.z;
  int b = bkh >> 3, khh = bkh & 7;
#pragma unroll
  for (int i = 0; i < 4; ++i) {
    int s = s0 + ty + i * 8;
    float v;
    if (s < 512) v = past[((size_t)bkh * 512 + s) * 128 + d0 + tx];
    else         v = bf2f(kvb[(size_t)(b * 2048 + s - 512) * 2048 + 1024 + khh * 128 + d0 + tx]);
    t[ty + i * 8][tx] = v;
  }
  __syncthreads();
#pragma unroll
  for (int i = 0; i < 4; ++i)
    vt[((size_t)bkh * 128 + d0 + ty + i * 8) * 2560 + s0 + tx] = f2bf(t[tx][ty + i * 8]);
}

// ---------------- flash attention fwd: 8 waves x 32 q, 32x32x16 MFMA ----------------
__global__ __launch_bounds__(512, 2) void attn_fwd(const u16* __restrict__ Q,
                                                   const u16* __restrict__ Kc,
                                                   const u16* __restrict__ Vt,
                                                   u16* __restrict__ Oa) {
  __shared__ u16 lds[2][16384];  // [buf][ Ks 64x128 | Vs 128x64 ]
  const int tid = threadIdx.x;
  const int w = tid >> 6, lane = tid & 63;
  const int c32 = lane & 31, hi = lane >> 5;
  const int qt = blockIdx.x, h = blockIdx.y, b = blockIdx.z;
  const int kh = h >> 2;
  const int q0 = qt * 256;
  const int qw = q0 + w * 32;
  const int qg = qw + c32;
  const float SCALE = 0.08838834764831845f;

  bf16x8 qf[8];
  const u16* qbase = Q + (size_t)(b * 2048 + qg) * 4096 + h * 128 + hi * 8;
#pragma unroll
  for (int kc = 0; kc < 8; ++kc) qf[kc] = *(const bf16x8*)(qbase + kc * 16);

  const int krow = w * 4 + (lane >> 4);
  const int koff = krow * 128 + (((lane & 15) ^ (krow & 7)) * 8);
  const int vrow = w * 8 + (lane >> 3);
  const int voff = vrow * 2560 + (((lane & 7) ^ (vrow & 7)) * 8);
  const u16* kp = Kc + (size_t)(b * 8 + kh) * 2560 * 128;
  const u16* vp = Vt + (size_t)(b * 8 + kh) * 128 * 2560;
  u16* ksd0 = &lds[0][w * 512]; u16* ksd1 = &lds[1][w * 512];
  u16* vsd0 = &lds[0][8192 + w * 512]; u16* vsd1 = &lds[1][8192 + w * 512];

  const int ntiles = 4 * qt + 12;

  gload_lds16(kp + koff, ksd0);
  gload_lds16(kp + koff + 4096, ksd0 + 4096);
  gload_lds16(vp + voff, vsd0);
  gload_lds16(vp + voff + 163840, vsd0 + 4096);

  float m_run = -1e30f, l_run = 0.f;
  f32x16 oacc[4] = {};
  const int s7 = c32 & 7;

  for (int t = 0; t < ntiles; ++t) {
    const int pb = t & 1;
    if (t + 1 < ntiles) {
      u16* kd = pb ? ksd0 : ksd1;
      u16* vd = pb ? vsd0 : vsd1;
      gload_lds16(kp + 8192 + koff, kd);
      gload_lds16(kp + 8192 + koff + 4096, kd + 4096);
      gload_lds16(vp + 64 + voff, vd);
      gload_lds16(vp + 64 + voff + 163840, vd + 4096);
      asm volatile("s_waitcnt vmcnt(4)" ::: "memory");
    } else {
      asm volatile("s_waitcnt vmcnt(0)" ::: "memory");
    }
    __builtin_amdgcn_s_barrier();

    const int dd = 512 + qw - t * 64;
    if (dd >= -31) {
      const u16* Ks = &lds[pb][0];
      const u16* Vs = &lds[pb][8192];

      f32x16 sc[2] = {};
#pragma unroll
      for (int kc = 0; kc < 8; ++kc) {
#pragma unroll
        for (int sb = 0; sb < 2; ++sb) {
          const int sr = sb * 32 + c32;
          bf16x8 kf = *(const bf16x8*)(Ks + sr * 128 + (((kc * 2 + hi) ^ s7) * 8));
          sc[sb] = __builtin_amdgcn_mfma_f32_32x32x16_bf16(kf, qf[kc], sc[sb], 0, 0, 0);
        }
      }

      if (dd < 63) {
        const int base = 4 * hi - c32;
#pragma unroll
        for (int sb = 0; sb < 2; ++sb)
#pragma unroll
          for (int r = 0; r < 16; ++r) {
            const int srow = sb * 32 + (r & 3) + 8 * (r >> 2);
            if (srow + base > dd) sc[sb][r] = -1e30f;
          }
      }

      float pmax = -1e30f;
#pragma unroll
      for (int sb = 0; sb < 2; ++sb)
#pragma unroll
        for (int r = 0; r < 16; ++r) pmax = fmaxf(pmax, sc[sb][r]);
      pmax = crossmax(pmax);

      if (__any(pmax > m_run + 64.f)) {
        const float mn = fmaxf(m_run, pmax);
        const float corr = __expf((m_run - mn) * SCALE);
#pragma unroll
        for (int db = 0; db < 4; ++db)
#pragma unroll
          for (int r = 0; r < 16; ++r) oacc[db][r] *= corr;
        l_run *= corr;
        m_run = mn;
      }

      const float nms = -m_run * SCALE;
      float ls = 0.f;
#pragma unroll
      for (int sb = 0; sb < 2; ++sb)
#pragma unroll
        for (int r = 0; r < 16; ++r) {
          float p = __expf(fmaf(sc[sb][r], SCALE, nms));
          sc[sb][r] = p;
          ls += p;
        }
      l_run += crosssum(ls);

      bf16x8 pa[4];
#pragma unroll
      for (int c = 0; c < 4; ++c) {
        const int sb = c >> 1, bb = (c & 1) * 8;
        u32 a  = cvtpk(sc[sb][bb + 0], sc[sb][bb + 1]);
        u32 b2 = cvtpk(sc[sb][bb + 2], sc[sb][bb + 3]);
        u32 c2 = cvtpk(sc[sb][bb + 4], sc[sb][bb + 5]);
        u32 d2 = cvtpk(sc[sb][bb + 6], sc[sb][bb + 7]);
        plswap(a, c2);
        plswap(b2, d2);
        union { u32 u[4]; bf16x8 v; } cv;
        cv.u[0] = a; cv.u[1] = b2; cv.u[2] = c2; cv.u[3] = d2;
        pa[c] = cv.v;
      }

#pragma unroll
      for (int c = 0; c < 4; ++c) {
#pragma unroll
        for (int db = 0; db < 4; ++db) {
          const int d = db * 32 + c32;
          bf16x8 vf = *(const bf16x8*)(Vs + d * 64 + (((c * 2 + hi) ^ s7) * 8));
          oacc[db] = __builtin_amdgcn_mfma_f32_32x32x16_bf16(vf, pa[c], oacc[db], 0, 0, 0);
        }
      }
    }
    __builtin_amdgcn_s_barrier();
    kp += 8192; vp += 64;
  }

  const float linv = 1.f / l_run;
  u16* ob = Oa + (size_t)(b * 2048 + qg) * 4096 + h * 128 + 4 * hi;
#pragma unroll
  for (int db = 0; db < 4; ++db)
#pragma unroll
    for (int rg = 0; rg < 4; ++rg) {
      u32x2 st;
      st[0] = cvtpk(oacc[db][rg * 4 + 0] * linv, oacc[db][rg * 4 + 1] * linv);
      st[1] = cvtpk(oacc[db][rg * 4 + 2] * linv, oacc[db][rg * 4 + 3] * linv);
      *(u32x2*)(ob + db * 32 + rg * 8) = st;
    }
}

extern "C" void kernel_launch(void* const* d_in, const int* in_sizes, int n_in,
                              void* d_out, int out_size, void* d_ws, size_t ws_size,
                              hipStream_t stream) {
  (void)in_sizes; (void)n_in; (void)out_size; (void)ws_size;
  const float* x  = (const float*)d_in[0];
  const float* pk = (const float*)d_in[2];
  const float* pv = (const float*)d_in[3];
  const float* Wq = (const float*)d_in[4];
  const float* Wk = (const float*)d_in[5];
  const float* Wv = (const float*)d_in[6];
  const float* Wo = (const float*)d_in[7];
  float* out = (float*)d_out;

  char* w = (char*)d_ws;  // peak 132 MB
  u16* xb  = (u16*)(w);                  // [0,32M)   x bf16 [4096,4096]; ao aliases later
  u16* wt  = (u16*)(w + 33554432);       // [32M,64M) transposed weights (reused)
  u16* qb  = (u16*)(w + 67108864);       // [64M,96M) Q bf16 [4096,4096]
  u16* kvb = (u16*)(w + 100663296);      // [96M,112M) KV bf16 [4096,2048]
  u16* kc  = (u16*)(w + 117440512);      // [112M,122M) Kc bf16 [2,8,2560,128]
  u16* vt  = (u16*)(w + 127926272);      // [122M,132M) Vt bf16 [2,8,128,2560]
  u16* ao  = xb;

  cast_x_kernel<<<8192, 256, 0, stream>>>(x, xb);
  transpose_cast<<<dim3(128, 128), 256, 0, stream>>>(Wq, wt, 4096, 4096);
  gemm8<u16><<<dim3(16, 16), 512, 0, stream>>>(xb, wt, qb, 4096, 4096, 4096);
  transpose_cast<<<dim3(32, 128), 256, 0, stream>>>(Wk, wt, 4096, 1024);
  transpose_cast<<<dim3(32, 128), 256, 0, stream>>>(Wv, wt + (size_t)1024 * 4096, 4096, 1024);
  gemm8<u16><<<dim3(8, 16), 512, 0, stream>>>(xb, wt, kvb, 4096, 2048, 4096);
  kcat<<<2560, 256, 0, stream>>>(pk, kvb, kc);
  vt_build<<<dim3(80, 4, 16), 256, 0, stream>>>(pv, kvb, vt);
  transpose_cast<<<dim3(128, 128), 256, 0, stream>>>(Wo, wt, 4096, 4096);
  attn_fwd<<<dim3(8, 32, 2), 512, 0, stream>>>(qb, kc, vt, ao);
  gemm8<float><<<dim3(16, 16), 512, 0, stream>>>(ao, wt, out, 4096, 4096, 4096);
}

// Round 5
// 758.577 us; speedup vs baseline: 1.4811x; 1.0948x over previous
//
#include <hip/hip_runtime.h>

using u16 = unsigned short;
using u32 = unsigned int;
using bf16x8 = __attribute__((ext_vector_type(8))) __bf16;
using f32x4  = __attribute__((ext_vector_type(4))) float;
using f32x16 = __attribute__((ext_vector_type(16))) float;
using u16x8  = __attribute__((ext_vector_type(8))) u16;
using u32x2  = __attribute__((ext_vector_type(2))) u32;

#define DEV static __device__ __forceinline__

DEV float bf2f(u16 u) { union { u32 i; float f; } c; c.i = ((u32)u) << 16; return c.f; }
DEV u16 f2bf(float f) {
  union { float f; u32 i; } c; c.f = f;
  u32 r = c.i + 0x7FFFu + ((c.i >> 16) & 1u);
  return (u16)(r >> 16);
}

// async global->LDS, 16B per lane; lds dest must be wave-uniform base (HW adds lane*16)
DEV void gload_lds16(const void* g, void* l) {
  __builtin_amdgcn_global_load_lds(
      (const __attribute__((address_space(1))) u32*)g,
      (__attribute__((address_space(3))) u32*)l, 16, 0, 0);
}

DEV u32 cvtpk(float lo, float hi) {
  u32 r;
  asm("v_cvt_pk_bf16_f32 %0, %1, %2" : "=v"(r) : "v"(lo), "v"(hi));
  return r;
}
DEV void plswap(u32& a, u32& b) {
  auto r = __builtin_amdgcn_permlane32_swap((int)a, (int)b, false, false);
  a = (u32)r[0]; b = (u32)r[1];
}
DEV float crossmax(float x) {
  union { float f; u32 i; } c; c.f = x;
  u32 a = c.i, b = c.i;
  plswap(a, b);
  union { u32 i; float f; } A, B; A.i = a; B.i = b;
  return fmaxf(A.f, B.f);
}
DEV float crosssum(float x) {
  union { float f; u32 i; } c; c.f = x;
  u32 a = c.i, b = c.i;
  plswap(a, b);
  union { u32 i; float f; } A, B; A.i = a; B.i = b;
  return A.f + B.f;
}

DEV void fence_barrier() {
  asm volatile("" ::: "memory");
  __builtin_amdgcn_s_barrier();
  asm volatile("" ::: "memory");
}

// ---------------- cast x: fp32 -> bf16, 8 elems/thread ----------------
__global__ __launch_bounds__(256) void cast_x_kernel(const float* __restrict__ x,
                                                     u16* __restrict__ xb) {
  size_t i = (size_t)blockIdx.x * 256 + threadIdx.x;
  const float4* s4 = (const float4*)(x + i * 8);
  float4 a = s4[0], c = s4[1];
  u16x8 o;
  o[0] = f2bf(a.x); o[1] = f2bf(a.y); o[2] = f2bf(a.z); o[3] = f2bf(a.w);
  o[4] = f2bf(c.x); o[5] = f2bf(c.y); o[6] = f2bf(c.z); o[7] = f2bf(c.w);
  *(u16x8*)(xb + i * 8) = o;
}

// ------------- W [K,N] fp32 -> Wt [N,K] bf16, tiled LDS transpose -------------
__global__ __launch_bounds__(256) void transpose_cast(const float* __restrict__ W,
                                                      u16* __restrict__ Wt, int K, int N) {
  __shared__ float t[32][33];
  int tx = threadIdx.x & 31, ty = threadIdx.x >> 5;
  int n0 = blockIdx.x * 32, k0 = blockIdx.y * 32;
#pragma unroll
  for (int i = 0; i < 4; ++i)
    t[ty + i * 8][tx] = W[(size_t)(k0 + ty + i * 8) * N + n0 + tx];
  __syncthreads();
#pragma unroll
  for (int i = 0; i < 4; ++i)
    Wt[(size_t)(n0 + ty + i * 8) * K + k0 + tx] = f2bf(t[tx][ty + i * 8]);
}

// ============ 256x256 8-phase GEMM: C[M,N] = A[M,K] * Bt[N,K]^T ============
// 8 waves (2M x 4N), per-wave 128x64 out, BK=64, 2 K-tiles per iteration.
// LDS 128 KiB: [buf][A 256p x 64k | B 256p x 64k]; XOR-swizzle (T2) via
// pre-swizzled global source + swizzled ds_read (both sides, same involution).
// vmcnt(4) only at phases 4 and 8 (T4); setprio around MFMA clusters (T5).

DEV int swap67(int p) { return (p & 63) | ((p & 64) << 1) | ((p & 128) >> 1); }
DEV int colmap(int p) { return (p & 31) | ((p & 96) << 1) | ((p >> 2) & 32); }

template <int PAR, int MH, int NH, bool VM, typename F>
DEV void gphase(const u16* lds, int wrp, int wcp, int c16, int g, int s7,
                f32x4 (&acc)[8][4], F&& stage) {
  bf16x8 af[4][2];
  bf16x8 bv[2][2];
#pragma unroll
  for (int fi = 0; fi < 4; ++fi) {
    const u16* rp = lds + PAR * 32768 + (MH * 128 + wrp + fi * 16 + c16) * 64;
    af[fi][0] = *(const bf16x8*)(rp + ((0 + g) ^ s7) * 8);
    af[fi][1] = *(const bf16x8*)(rp + ((4 + g) ^ s7) * 8);
  }
#pragma unroll
  for (int fj = 0; fj < 2; ++fj) {
    const u16* rp = lds + PAR * 32768 + 16384 + (NH * 128 + wcp + fj * 16 + c16) * 64;
    bv[fj][0] = *(const bf16x8*)(rp + ((0 + g) ^ s7) * 8);
    bv[fj][1] = *(const bf16x8*)(rp + ((4 + g) ^ s7) * 8);
  }
  stage();
  if (VM) asm volatile("s_waitcnt vmcnt(4)" ::: "memory");
  fence_barrier();
  __builtin_amdgcn_s_setprio(1);
#pragma unroll
  for (int fi = 0; fi < 4; ++fi)
#pragma unroll
    for (int fj = 0; fj < 2; ++fj) {
      acc[MH * 4 + fi][NH * 2 + fj] = __builtin_amdgcn_mfma_f32_16x16x32_bf16(
          af[fi][0], bv[fj][0], acc[MH * 4 + fi][NH * 2 + fj], 0, 0, 0);
      acc[MH * 4 + fi][NH * 2 + fj] = __builtin_amdgcn_mfma_f32_16x16x32_bf16(
          af[fi][1], bv[fj][1], acc[MH * 4 + fi][NH * 2 + fj], 0, 0, 0);
    }
  __builtin_amdgcn_s_setprio(0);
  fence_barrier();
}

template <typename CT>
__global__ __launch_bounds__(512, 2) void gemm8(const u16* __restrict__ A,
                                                const u16* __restrict__ Bt,
                                                CT* __restrict__ C, int M, int N, int K) {
  __shared__ u16 lds[65536];  // 128 KiB
  const int tid = threadIdx.x;
  const int w = tid >> 6, lane = tid & 63;
  const int g = lane >> 4, c16 = lane & 15, s7 = c16 & 7;
  // bijective XCD swizzle (nwg % 8 == 0 for all grids used)
  const int nwg = gridDim.x * gridDim.y;
  const int bid0 = blockIdx.y * gridDim.x + blockIdx.x;
  const int sb = (bid0 & 7) * (nwg >> 3) + (bid0 >> 3);
  const int bn = (sb % gridDim.x) * 256;
  const int bm = (sb / gridDim.x) * 256;
  const int wr = (w >> 2) * 128, wc = (w & 3) * 64;   // wave's C offsets
  const int wrp = (w >> 2) * 64, wcp = (w & 3) * 32;  // physical LDS bases

  const int lr = lane >> 3;
  const int swz = ((lane & 7) ^ lr) * 8;  // pre-swizzled k-block (involution)
  u32 aOff[2][2], bOff[2][2];
#pragma unroll
  for (int h = 0; h < 2; ++h)
#pragma unroll
    for (int j = 0; j < 2; ++j) {
      int pb = h * 128 + (w * 2 + j) * 8;
      aOff[h][j] = (u32)(bm + swap67(pb) + lr) * (u32)K + swz;
      bOff[h][j] = (u32)(bn + colmap(pb) + lr) * (u32)K + swz;
    }
  auto stA = [&](int par, int h, int j, int ko) {
    gload_lds16(A + aOff[h][j] + ko, (u16*)lds + par * 32768 + h * 8192 + (w * 2 + j) * 512);
  };
  auto stB = [&](int par, int h, int j, int ko) {
    gload_lds16(Bt + bOff[h][j] + ko,
                (u16*)lds + par * 32768 + 16384 + h * 8192 + (w * 2 + j) * 512);
  };

  f32x4 acc[8][4] = {};

  // prologue: tile0 (all 4 halves) -> buf0; tile1 (AH0,BH0) -> buf1
  stA(0, 0, 0, 0); stA(0, 0, 1, 0); stB(0, 0, 0, 0); stB(0, 0, 1, 0);
  stA(0, 1, 0, 0); stA(0, 1, 1, 0); stB(0, 1, 0, 0); stB(0, 1, 1, 0);
  stA(1, 0, 0, 64); stA(1, 0, 1, 64); stB(1, 0, 0, 64); stB(1, 0, 1, 64);
  asm volatile("s_waitcnt vmcnt(4)" ::: "memory");
  fence_barrier();

  for (int kb = 64; kb < K; kb += 128) {
    const int kc = kb + 64, kd = kb + 128;
    const bool hc = kc < K, hd = kd < K;
    gphase<0, 0, 0, false>(lds, wrp, wcp, c16, g, s7, acc, [&] {
      stA(1, 1, 0, kb); stA(1, 1, 1, kb); stB(1, 1, 0, kb); stB(1, 1, 1, kb);
    });
    gphase<0, 0, 1, false>(lds, wrp, wcp, c16, g, s7, acc, [&] {});
    gphase<0, 1, 0, false>(lds, wrp, wcp, c16, g, s7, acc, [&] {
      if (hc) { stA(0, 0, 0, kc); stA(0, 0, 1, kc); }
    });
    gphase<0, 1, 1, true>(lds, wrp, wcp, c16, g, s7, acc, [&] {
      if (hc) { stB(0, 0, 0, kc); stB(0, 0, 1, kc); }
    });
    gphase<1, 0, 0, false>(lds, wrp, wcp, c16, g, s7, acc, [&] {
      if (hc) { stA(0, 1, 0, kc); stA(0, 1, 1, kc); stB(0, 1, 0, kc); stB(0, 1, 1, kc); }
    });
    gphase<1, 0, 1, false>(lds, wrp, wcp, c16, g, s7, acc, [&] {});
    gphase<1, 1, 0, false>(lds, wrp, wcp, c16, g, s7, acc, [&] {
      if (hd) { stA(1, 0, 0, kd); stA(1, 0, 1, kd); }
    });
    gphase<1, 1, 1, true>(lds, wrp, wcp, c16, g, s7, acc, [&] {
      if (hd) { stB(1, 0, 0, kd); stB(1, 0, 1, kd); }
    });
  }

#pragma unroll
  for (int mf = 0; mf < 8; ++mf)
#pragma unroll
    for (int nf = 0; nf < 4; ++nf)
#pragma unroll
      for (int r = 0; r < 4; ++r) {
        int row = bm + wr + (mf >> 2) * 64 + (mf & 3) * 16 + g * 4 + r;
        int col = bn + wc + (nf >> 1) * 32 + (nf & 1) * 16 + c16;
        float v = acc[mf][nf][r];
        if constexpr (sizeof(CT) == 2) C[(size_t)row * N + col] = f2bf(v);
        else                           C[(size_t)row * N + col] = v;
      }
}

// ---- K concat: past_k fp32 + kvb(K cols) bf16 -> Kc bf16 [B,KH,S,128] ----
__global__ __launch_bounds__(256) void kcat(const float* __restrict__ past,
                                            const u16* __restrict__ kvb,
                                            u16* __restrict__ out) {
  int idx = blockIdx.x * 256 + threadIdx.x;  // (b,kh,s,d8)
  int bkh = idx / 40960;
  int rem = idx - bkh * 40960;
  int s = rem >> 4;
  int d0 = (rem & 15) * 8;
  u16x8 o;
  if (s < 512) {
    const float4* s4 = (const float4*)(past + ((size_t)bkh * 512 + s) * 128 + d0);
    float4 a = s4[0], c = s4[1];
    o[0] = f2bf(a.x); o[1] = f2bf(a.y); o[2] = f2bf(a.z); o[3] = f2bf(a.w);
    o[4] = f2bf(c.x); o[5] = f2bf(c.y); o[6] = f2bf(c.z); o[7] = f2bf(c.w);
  } else {
    int b = bkh >> 3, khh = bkh & 7;
    o = *(const u16x8*)(kvb + (size_t)(b * 2048 + s - 512) * 2048 + khh * 128 + d0);
  }
  *(u16x8*)(out + (size_t)idx * 8) = o;
}

// ---- V concat + transpose: -> Vt bf16 [B,KH,128,2560] ----
__global__ __launch_bounds__(256) void vt_build(const float* __restrict__ past,
                                                const u16* __restrict__ kvb,
                                                u16* __restrict__ vt) {
  __shared__ float t[32][33];
  int tx = threadIdx.x & 31, ty = threadIdx.x >> 5;
  int s0 = blockIdx.x * 32, d0 = blockIdx.y * 32, bkh = blockIdx.z;
  int b = bkh >> 3, khh = bkh & 7;
#pragma unroll
  for (int i = 0; i < 4; ++i) {
    int s = s0 + ty + i * 8;
    float v;
    if (s < 512) v = past[((size_t)bkh * 512 + s) * 128 + d0 + tx];
    else         v = bf2f(kvb[(size_t)(b * 2048 + s - 512) * 2048 + 1024 + khh * 128 + d0 + tx]);
    t[ty + i * 8][tx] = v;
  }
  __syncthreads();
#pragma unroll
  for (int i = 0; i < 4; ++i)
    vt[((size_t)bkh * 128 + d0 + ty + i * 8) * 2560 + s0 + tx] = f2bf(t[tx][ty + i * 8]);
}

// ---------------- flash attention fwd: 8 waves x 32 q, 32x32x16 MFMA ----------------
// Grid: 1-D 512 blocks. Decode pairs heavy/light q-tiles on co-resident CU slots
// and decorrelates qt from bid%8 (XCD) — balanced makespan (52 tiles per CU).
__global__ __launch_bounds__(512, 2) void attn_fwd(const u16* __restrict__ Q,
                                                   const u16* __restrict__ Kc,
                                                   const u16* __restrict__ Vt,
                                                   u16* __restrict__ Oa) {
  __shared__ u16 lds[2][16384];  // [buf][ Ks 64x128 | Vs 128x64 ]
  const int tid = threadIdx.x;
  const int w = tid >> 6, lane = tid & 63;
  const int c32 = lane & 31, hi = lane >> 5;
  const int bid = blockIdx.x;
  const int b = bid >> 8;                 // batch = co-residency slot
  const int q8 = (bid >> 5) & 7;
  const int qt = b ? 7 - q8 : q8;         // complementary pairing: work a + (7-a) = const
  const int h = bid & 31;
  const int kh = h >> 2;
  const int q0 = qt * 256;
  const int qw = q0 + w * 32;
  const int qg = qw + c32;
  const float SCALE = 0.08838834764831845f;

  bf16x8 qf[8];
  const u16* qbase = Q + (size_t)(b * 2048 + qg) * 4096 + h * 128 + hi * 8;
#pragma unroll
  for (int kc = 0; kc < 8; ++kc) qf[kc] = *(const bf16x8*)(qbase + kc * 16);

  const int krow = w * 4 + (lane >> 4);
  const int koff = krow * 128 + (((lane & 15) ^ (krow & 7)) * 8);
  const int vrow = w * 8 + (lane >> 3);
  const int voff = vrow * 2560 + (((lane & 7) ^ (vrow & 7)) * 8);
  const u16* kp = Kc + (size_t)(b * 8 + kh) * 2560 * 128;
  const u16* vp = Vt + (size_t)(b * 8 + kh) * 128 * 2560;
  u16* ksd0 = &lds[0][w * 512]; u16* ksd1 = &lds[1][w * 512];
  u16* vsd0 = &lds[0][8192 + w * 512]; u16* vsd1 = &lds[1][8192 + w * 512];

  const int ntiles = 4 * qt + 12;

  gload_lds16(kp + koff, ksd0);
  gload_lds16(kp + koff + 4096, ksd0 + 4096);
  gload_lds16(vp + voff, vsd0);
  gload_lds16(vp + voff + 163840, vsd0 + 4096);

  float m_run = -1e30f, l_run = 0.f;
  f32x16 oacc[4] = {};
  const int s7 = c32 & 7;

  for (int t = 0; t < ntiles; ++t) {
    const int pb = t & 1;
    if (t + 1 < ntiles) {
      u16* kd = pb ? ksd0 : ksd1;
      u16* vd = pb ? vsd0 : vsd1;
      gload_lds16(kp + 8192 + koff, kd);
      gload_lds16(kp + 8192 + koff + 4096, kd + 4096);
      gload_lds16(vp + 64 + voff, vd);
      gload_lds16(vp + 64 + voff + 163840, vd + 4096);
      asm volatile("s_waitcnt vmcnt(4)" ::: "memory");
    } else {
      asm volatile("s_waitcnt vmcnt(0)" ::: "memory");
    }
    __builtin_amdgcn_s_barrier();

    const int dd = 512 + qw - t * 64;
    if (dd >= -31) {
      const u16* Ks = &lds[pb][0];
      const u16* Vs = &lds[pb][8192];

      f32x16 sc[2] = {};
#pragma unroll
      for (int kc = 0; kc < 8; ++kc) {
#pragma unroll
        for (int sb = 0; sb < 2; ++sb) {
          const int sr = sb * 32 + c32;
          bf16x8 kf = *(const bf16x8*)(Ks + sr * 128 + (((kc * 2 + hi) ^ s7) * 8));
          sc[sb] = __builtin_amdgcn_mfma_f32_32x32x16_bf16(kf, qf[kc], sc[sb], 0, 0, 0);
        }
      }

      if (dd < 63) {
        const int base = 4 * hi - c32;
#pragma unroll
        for (int sb = 0; sb < 2; ++sb)
#pragma unroll
          for (int r = 0; r < 16; ++r) {
            const int srow = sb * 32 + (r & 3) + 8 * (r >> 2);
            if (srow + base > dd) sc[sb][r] = -1e30f;
          }
      }

      float pmax = -1e30f;
#pragma unroll
      for (int sb = 0; sb < 2; ++sb)
#pragma unroll
        for (int r = 0; r < 16; ++r) pmax = fmaxf(pmax, sc[sb][r]);
      pmax = crossmax(pmax);

      if (__any(pmax > m_run + 64.f)) {
        const float mn = fmaxf(m_run, pmax);
        const float corr = __expf((m_run - mn) * SCALE);
#pragma unroll
        for (int db = 0; db < 4; ++db)
#pragma unroll
          for (int r = 0; r < 16; ++r) oacc[db][r] *= corr;
        l_run *= corr;
        m_run = mn;
      }

      const float nms = -m_run * SCALE;
      float ls = 0.f;
#pragma unroll
      for (int sb = 0; sb < 2; ++sb)
#pragma unroll
        for (int r = 0; r < 16; ++r) {
          float p = __expf(fmaf(sc[sb][r], SCALE, nms));
          sc[sb][r] = p;
          ls += p;
        }
      l_run += crosssum(ls);

      bf16x8 pa[4];
#pragma unroll
      for (int c = 0; c < 4; ++c) {
        const int sb = c >> 1, bb = (c & 1) * 8;
        u32 a  = cvtpk(sc[sb][bb + 0], sc[sb][bb + 1]);
        u32 b2 = cvtpk(sc[sb][bb + 2], sc[sb][bb + 3]);
        u32 c2 = cvtpk(sc[sb][bb + 4], sc[sb][bb + 5]);
        u32 d2 = cvtpk(sc[sb][bb + 6], sc[sb][bb + 7]);
        plswap(a, c2);
        plswap(b2, d2);
        union { u32 u[4]; bf16x8 v; } cv;
        cv.u[0] = a; cv.u[1] = b2; cv.u[2] = c2; cv.u[3] = d2;
        pa[c] = cv.v;
      }

#pragma unroll
      for (int c = 0; c < 4; ++c) {
#pragma unroll
        for (int db = 0; db < 4; ++db) {
          const int d = db * 32 + c32;
          bf16x8 vf = *(const bf16x8*)(Vs + d * 64 + (((c * 2 + hi) ^ s7) * 8));
          oacc[db] = __builtin_amdgcn_mfma_f32_32x32x16_bf16(vf, pa[c], oacc[db], 0, 0, 0);
        }
      }
    }
    __builtin_amdgcn_s_barrier();
    kp += 8192; vp += 64;
  }

  const float linv = 1.f / l_run;
  u16* ob = Oa + (size_t)(b * 2048 + qg) * 4096 + h * 128 + 4 * hi;
#pragma unroll
  for (int db = 0; db < 4; ++db)
#pragma unroll
    for (int rg = 0; rg < 4; ++rg) {
      u32x2 st;
      st[0] = cvtpk(oacc[db][rg * 4 + 0] * linv, oacc[db][rg * 4 + 1] * linv);
      st[1] = cvtpk(oacc[db][rg * 4 + 2] * linv, oacc[db][rg * 4 + 3] * linv);
      *(u32x2*)(ob + db * 32 + rg * 8) = st;
    }
}

extern "C" void kernel_launch(void* const* d_in, const int* in_sizes, int n_in,
                              void* d_out, int out_size, void* d_ws, size_t ws_size,
                              hipStream_t stream) {
  (void)in_sizes; (void)n_in; (void)out_size; (void)ws_size;
  const float* x  = (const float*)d_in[0];
  const float* pk = (const float*)d_in[2];
  const float* pv = (const float*)d_in[3];
  const float* Wq = (const float*)d_in[4];
  const float* Wk = (const float*)d_in[5];
  const float* Wv = (const float*)d_in[6];
  const float* Wo = (const float*)d_in[7];
  float* out = (float*)d_out;

  char* w = (char*)d_ws;  // peak 132 MB
  u16* xb  = (u16*)(w);                  // [0,32M)   x bf16 [4096,4096]; ao aliases later
  u16* wt  = (u16*)(w + 33554432);       // [32M,64M) transposed weights (reused)
  u16* qb  = (u16*)(w + 67108864);       // [64M,96M) Q bf16 [4096,4096]
  u16* kvb = (u16*)(w + 100663296);      // [96M,112M) KV bf16 [4096,2048]
  u16* kc  = (u16*)(w + 117440512);      // [112M,122M) Kc bf16 [2,8,2560,128]
  u16* vt  = (u16*)(w + 127926272);      // [122M,132M) Vt bf16 [2,8,128,2560]
  u16* ao  = xb;

  cast_x_kernel<<<8192, 256, 0, stream>>>(x, xb);
  transpose_cast<<<dim3(128, 128), 256, 0, stream>>>(Wq, wt, 4096, 4096);
  gemm8<u16><<<dim3(16, 16), 512, 0, stream>>>(xb, wt, qb, 4096, 4096, 4096);
  transpose_cast<<<dim3(32, 128), 256, 0, stream>>>(Wk, wt, 4096, 1024);
  transpose_cast<<<dim3(32, 128), 256, 0, stream>>>(Wv, wt + (size_t)1024 * 4096, 4096, 1024);
  gemm8<u16><<<dim3(8, 16), 512, 0, stream>>>(xb, wt, kvb, 4096, 2048, 4096);
  kcat<<<2560, 256, 0, stream>>>(pk, kvb, kc);
  vt_build<<<dim3(80, 4, 16), 256, 0, stream>>>(pv, kvb, vt);
  transpose_cast<<<dim3(128, 128), 256, 0, stream>>>(Wo, wt, 4096, 4096);
  attn_fwd<<<512, 512, 0, stream>>>(qb, kc, vt, ao);
  gemm8<float><<<dim3(16, 16), 512, 0, stream>>>(ao, wt, out, 4096, 4096, 4096);
}

// Round 6
// 687.646 us; speedup vs baseline: 1.6339x; 1.1032x over previous
//
#include <hip/hip_runtime.h>

using u16 = unsigned short;
using u32 = unsigned int;
using bf16x8 = __attribute__((ext_vector_type(8))) __bf16;
using f32x4  = __attribute__((ext_vector_type(4))) float;
using f32x16 = __attribute__((ext_vector_type(16))) float;
using u16x8  = __attribute__((ext_vector_type(8))) u16;
using u32x2  = __attribute__((ext_vector_type(2))) u32;

#define DEV static __device__ __forceinline__

DEV float bf2f(u16 u) { union { u32 i; float f; } c; c.i = ((u32)u) << 16; return c.f; }
DEV u16 f2bf(float f) {
  union { float f; u32 i; } c; c.f = f;
  u32 r = c.i + 0x7FFFu + ((c.i >> 16) & 1u);
  return (u16)(r >> 16);
}

// async global->LDS, 16B per lane; lds dest must be wave-uniform base (HW adds lane*16)
DEV void gload_lds16(const void* g, void* l) {
  __builtin_amdgcn_global_load_lds(
      (const __attribute__((address_space(1))) u32*)g,
      (__attribute__((address_space(3))) u32*)l, 16, 0, 0);
}

DEV u32 cvtpk(float lo, float hi) {
  u32 r;
  asm("v_cvt_pk_bf16_f32 %0, %1, %2" : "=v"(r) : "v"(lo), "v"(hi));
  return r;
}
DEV void plswap(u32& a, u32& b) {
  auto r = __builtin_amdgcn_permlane32_swap((int)a, (int)b, false, false);
  a = (u32)r[0]; b = (u32)r[1];
}
DEV float crossmax(float x) {
  union { float f; u32 i; } c; c.f = x;
  u32 a = c.i, b = c.i;
  plswap(a, b);
  union { u32 i; float f; } A, B; A.i = a; B.i = b;
  return fmaxf(A.f, B.f);
}
DEV float crosssum(float x) {
  union { float f; u32 i; } c; c.f = x;
  u32 a = c.i, b = c.i;
  plswap(a, b);
  union { u32 i; float f; } A, B; A.i = a; B.i = b;
  return A.f + B.f;
}

DEV void fence_barrier() {
  asm volatile("" ::: "memory");
  __builtin_amdgcn_s_barrier();
  asm volatile("" ::: "memory");
}

// ---------------- cast x: fp32 -> bf16, 8 elems/thread ----------------
__global__ __launch_bounds__(256) void cast_x_kernel(const float* __restrict__ x,
                                                     u16* __restrict__ xb) {
  size_t i = (size_t)blockIdx.x * 256 + threadIdx.x;
  const float4* s4 = (const float4*)(x + i * 8);
  float4 a = s4[0], c = s4[1];
  u16x8 o;
  o[0] = f2bf(a.x); o[1] = f2bf(a.y); o[2] = f2bf(a.z); o[3] = f2bf(a.w);
  o[4] = f2bf(c.x); o[5] = f2bf(c.y); o[6] = f2bf(c.z); o[7] = f2bf(c.w);
  *(u16x8*)(xb + i * 8) = o;
}

// ------------- W [K,N] fp32 -> Wt [N,K] bf16, tiled LDS transpose -------------
__global__ __launch_bounds__(256) void transpose_cast(const float* __restrict__ W,
                                                      u16* __restrict__ Wt, int K, int N) {
  __shared__ float t[32][33];
  int tx = threadIdx.x & 31, ty = threadIdx.x >> 5;
  int n0 = blockIdx.x * 32, k0 = blockIdx.y * 32;
#pragma unroll
  for (int i = 0; i < 4; ++i)
    t[ty + i * 8][tx] = W[(size_t)(k0 + ty + i * 8) * N + n0 + tx];
  __syncthreads();
#pragma unroll
  for (int i = 0; i < 4; ++i)
    Wt[(size_t)(n0 + ty + i * 8) * K + k0 + tx] = f2bf(t[tx][ty + i * 8]);
}

// ============ 256x256 8-phase GEMM: C[M,N] = A[M,K] * Bt[N,K]^T ============
// 8 waves (2M x 4N), per-wave 128x64 out, BK=64, 2 K-tiles per iteration.
// Persistent register fragments: af (A, shared across NH-pair), bv[NH] (B, held
// across MH-pair) -> 48 ds_read_b128 per iteration per wave (the minimum).
// XOR-swizzle (T2) via pre-swizzled global source + swizzled ds_read.
// vmcnt(4) only at phases 4 and 8 (T4); setprio around MFMA clusters (T5).
// Optional blockIdx.z split-K: A/Bt advance by z*K, C selects C/C2.

DEV int swap67(int p) { return (p & 63) | ((p & 64) << 1) | ((p & 128) >> 1); }
DEV int colmap(int p) { return (p & 31) | ((p & 96) << 1) | ((p >> 2) & 32); }

template <int PAR, int MH, int NH, bool LA, bool LB, bool VM, typename F>
DEV void gphase(const u16* lds, int wrp, int wcp, int c16, int g, int s7,
                bf16x8 (&af)[4][2], bf16x8 (&bv)[2][2][2],
                f32x4 (&acc)[8][4], bool pre_drain, F&& stage) {
  if (pre_drain) asm volatile("s_waitcnt vmcnt(0)" ::: "memory");  // K-tail only
  if constexpr (LA) {
#pragma unroll
    for (int fi = 0; fi < 4; ++fi) {
      const u16* rp = lds + PAR * 32768 + (MH * 128 + wrp + fi * 16 + c16) * 64;
      af[fi][0] = *(const bf16x8*)(rp + ((0 + g) ^ s7) * 8);
      af[fi][1] = *(const bf16x8*)(rp + ((4 + g) ^ s7) * 8);
    }
  }
  if constexpr (LB) {
#pragma unroll
    for (int fj = 0; fj < 2; ++fj) {
      const u16* rp = lds + PAR * 32768 + 16384 + (NH * 128 + wcp + fj * 16 + c16) * 64;
      bv[NH][fj][0] = *(const bf16x8*)(rp + ((0 + g) ^ s7) * 8);
      bv[NH][fj][1] = *(const bf16x8*)(rp + ((4 + g) ^ s7) * 8);
    }
  }
  stage();
  if (VM) asm volatile("s_waitcnt vmcnt(4)" ::: "memory");
  fence_barrier();
  __builtin_amdgcn_s_setprio(1);
#pragma unroll
  for (int fi = 0; fi < 4; ++fi)
#pragma unroll
    for (int fj = 0; fj < 2; ++fj) {
      acc[MH * 4 + fi][NH * 2 + fj] = __builtin_amdgcn_mfma_f32_16x16x32_bf16(
          af[fi][0], bv[NH][fj][0], acc[MH * 4 + fi][NH * 2 + fj], 0, 0, 0);
      acc[MH * 4 + fi][NH * 2 + fj] = __builtin_amdgcn_mfma_f32_16x16x32_bf16(
          af[fi][1], bv[NH][fj][1], acc[MH * 4 + fi][NH * 2 + fj], 0, 0, 0);
    }
  __builtin_amdgcn_s_setprio(0);
  fence_barrier();
}

template <typename CT>
__global__ __launch_bounds__(512, 2) void gemm8(const u16* __restrict__ A,
                                                const u16* __restrict__ Bt,
                                                CT* __restrict__ C, CT* __restrict__ C2,
                                                int M, int N, int K, int lda) {
  __shared__ u16 lds[65536];  // 128 KiB
  const int tid = threadIdx.x;
  const int w = tid >> 6, lane = tid & 63;
  const int g = lane >> 4, c16 = lane & 15, s7 = c16 & 7;
  // split-K via blockIdx.z
  A += (size_t)blockIdx.z * K;
  Bt += (size_t)blockIdx.z * K;
  CT* Cw = blockIdx.z ? C2 : C;
  // bijective XCD swizzle (nwg % 8 == 0 for all grids used)
  const int nwg = gridDim.x * gridDim.y;
  const int bid0 = blockIdx.y * gridDim.x + blockIdx.x;
  const int sb = (bid0 & 7) * (nwg >> 3) + (bid0 >> 3);
  const int bn = (sb % gridDim.x) * 256;
  const int bm = (sb / gridDim.x) * 256;
  const int wr = (w >> 2) * 128, wc = (w & 3) * 64;   // wave's C offsets
  const int wrp = (w >> 2) * 64, wcp = (w & 3) * 32;  // physical LDS bases

  const int lr = lane >> 3;
  const int swz = ((lane & 7) ^ lr) * 8;  // pre-swizzled k-block (involution)
  u32 aOff[2][2], bOff[2][2];
#pragma unroll
  for (int h = 0; h < 2; ++h)
#pragma unroll
    for (int j = 0; j < 2; ++j) {
      int pb = h * 128 + (w * 2 + j) * 8;
      aOff[h][j] = (u32)(bm + swap67(pb) + lr) * (u32)lda + swz;
      bOff[h][j] = (u32)(bn + colmap(pb) + lr) * (u32)lda + swz;
    }
  auto stA = [&](int par, int h, int j, int ko) {
    gload_lds16(A + aOff[h][j] + ko, (u16*)lds + par * 32768 + h * 8192 + (w * 2 + j) * 512);
  };
  auto stB = [&](int par, int h, int j, int ko) {
    gload_lds16(Bt + bOff[h][j] + ko,
                (u16*)lds + par * 32768 + 16384 + h * 8192 + (w * 2 + j) * 512);
  };

  f32x4 acc[8][4] = {};
  bf16x8 af[4][2];
  bf16x8 bv[2][2][2];

  // prologue: tile0 (all 4 halves) -> buf0; tile1 (AH0,BH0) -> buf1
  stA(0, 0, 0, 0); stA(0, 0, 1, 0); stB(0, 0, 0, 0); stB(0, 0, 1, 0);
  stA(0, 1, 0, 0); stA(0, 1, 1, 0); stB(0, 1, 0, 0); stB(0, 1, 1, 0);
  stA(1, 0, 0, 64); stA(1, 0, 1, 64); stB(1, 0, 0, 64); stB(1, 0, 1, 64);
  asm volatile("s_waitcnt vmcnt(4)" ::: "memory");
  fence_barrier();

  for (int kb = 64; kb < K; kb += 128) {
    const int kc = kb + 64, kd = kb + 128;
    const bool hc = kc < K, hd = kd < K;
    gphase<0, 0, 0, true, true, false>(lds, wrp, wcp, c16, g, s7, af, bv, acc, false, [&] {
      stA(1, 1, 0, kb); stA(1, 1, 1, kb); stB(1, 1, 0, kb); stB(1, 1, 1, kb);
    });
    gphase<0, 0, 1, false, true, false>(lds, wrp, wcp, c16, g, s7, af, bv, acc, false, [&] {});
    gphase<0, 1, 0, true, false, false>(lds, wrp, wcp, c16, g, s7, af, bv, acc, false, [&] {
      if (hc) { stA(0, 0, 0, kc); stA(0, 0, 1, kc); }
    });
    gphase<0, 1, 1, false, false, true>(lds, wrp, wcp, c16, g, s7, af, bv, acc, false, [&] {
      if (hc) { stB(0, 0, 0, kc); stB(0, 0, 1, kc); }
    });
    // pre_drain at K-tail: ph4's vmcnt(4) couldn't drain tile-b H1 when nothing was staged
    gphase<1, 0, 0, true, true, false>(lds, wrp, wcp, c16, g, s7, af, bv, acc, !hc, [&] {
      if (hc) { stA(0, 1, 0, kc); stA(0, 1, 1, kc); stB(0, 1, 0, kc); stB(0, 1, 1, kc); }
    });
    gphase<1, 0, 1, false, true, false>(lds, wrp, wcp, c16, g, s7, af, bv, acc, false, [&] {});
    gphase<1, 1, 0, true, false, false>(lds, wrp, wcp, c16, g, s7, af, bv, acc, false, [&] {
      if (hd) { stA(1, 0, 0, kd); stA(1, 0, 1, kd); }
    });
    gphase<1, 1, 1, false, false, true>(lds, wrp, wcp, c16, g, s7, af, bv, acc, false, [&] {
      if (hd) { stB(1, 0, 0, kd); stB(1, 0, 1, kd); }
    });
  }

#pragma unroll
  for (int mf = 0; mf < 8; ++mf)
#pragma unroll
    for (int nf = 0; nf < 4; ++nf)
#pragma unroll
      for (int r = 0; r < 4; ++r) {
        int row = bm + wr + (mf >> 2) * 64 + (mf & 3) * 16 + g * 4 + r;
        int col = bn + wc + (nf >> 1) * 32 + (nf & 1) * 16 + c16;
        float v = acc[mf][nf][r];
        if constexpr (sizeof(CT) == 2) Cw[(size_t)row * N + col] = f2bf(v);
        else                           Cw[(size_t)row * N + col] = v;
      }
}

// ---- K concat: past_k fp32 + split-K partial sums -> Kc bf16 [B,KH,S,128] ----
__global__ __launch_bounds__(256) void kcat(const float* __restrict__ past,
                                            const u16* __restrict__ kvb,
                                            const u16* __restrict__ kvb2,
                                            u16* __restrict__ out) {
  int idx = blockIdx.x * 256 + threadIdx.x;  // (b,kh,s,d8)
  int bkh = idx / 40960;
  int rem = idx - bkh * 40960;
  int s = rem >> 4;
  int d0 = (rem & 15) * 8;
  u16x8 o;
  if (s < 512) {
    const float4* s4 = (const float4*)(past + ((size_t)bkh * 512 + s) * 128 + d0);
    float4 a = s4[0], c = s4[1];
    o[0] = f2bf(a.x); o[1] = f2bf(a.y); o[2] = f2bf(a.z); o[3] = f2bf(a.w);
    o[4] = f2bf(c.x); o[5] = f2bf(c.y); o[6] = f2bf(c.z); o[7] = f2bf(c.w);
  } else {
    int b = bkh >> 3, khh = bkh & 7;
    size_t off = (size_t)(b * 2048 + s - 512) * 2048 + khh * 128 + d0;
    u16x8 k1 = *(const u16x8*)(kvb + off);
    u16x8 k2 = *(const u16x8*)(kvb2 + off);
#pragma unroll
    for (int j = 0; j < 8; ++j) o[j] = f2bf(bf2f(k1[j]) + bf2f(k2[j]));
  }
  *(u16x8*)(out + (size_t)idx * 8) = o;
}

// ---- V concat + transpose (+ split-K sum): -> Vt bf16 [B,KH,128,2560] ----
__global__ __launch_bounds__(256) void vt_build(const float* __restrict__ past,
                                                const u16* __restrict__ kvb,
                                                const u16* __restrict__ kvb2,
                                                u16* __restrict__ vt) {
  __shared__ float t[32][33];
  int tx = threadIdx.x & 31, ty = threadIdx.x >> 5;
  int s0 = blockIdx.x * 32, d0 = blockIdx.y * 32, bkh = blockIdx.z;
  int b = bkh >> 3, khh = bkh & 7;
#pragma unroll
  for (int i = 0; i < 4; ++i) {
    int s = s0 + ty + i * 8;
    float v;
    if (s < 512) {
      v = past[((size_t)bkh * 512 + s) * 128 + d0 + tx];
    } else {
      size_t off = (size_t)(b * 2048 + s - 512) * 2048 + 1024 + khh * 128 + d0 + tx;
      v = bf2f(kvb[off]) + bf2f(kvb2[off]);
    }
    t[ty + i * 8][tx] = v;
  }
  __syncthreads();
#pragma unroll
  for (int i = 0; i < 4; ++i)
    vt[((size_t)bkh * 128 + d0 + ty + i * 8) * 2560 + s0 + tx] = f2bf(t[tx][ty + i * 8]);
}

// ---------------- flash attention fwd: 8 waves x 32 q, 32x32x16 MFMA ----------------
// Grid: 1-D 512 blocks. Decode pairs heavy/light q-tiles on co-resident CU slots
// and decorrelates qt from bid%8 (XCD) — balanced makespan (52 tiles per CU).
__global__ __launch_bounds__(512, 2) void attn_fwd(const u16* __restrict__ Q,
                                                   const u16* __restrict__ Kc,
                                                   const u16* __restrict__ Vt,
                                                   u16* __restrict__ Oa) {
  __shared__ u16 lds[2][16384];  // [buf][ Ks 64x128 | Vs 128x64 ]
  const int tid = threadIdx.x;
  const int w = tid >> 6, lane = tid & 63;
  const int c32 = lane & 31, hi = lane >> 5;
  const int bid = blockIdx.x;
  const int b = bid >> 8;                 // batch = co-residency slot
  const int q8 = (bid >> 5) & 7;
  const int qt = b ? 7 - q8 : q8;         // complementary pairing: work a + (7-a) = const
  const int h = bid & 31;
  const int kh = h >> 2;
  const int q0 = qt * 256;
  const int qw = q0 + w * 32;
  const int qg = qw + c32;
  const float SCALE = 0.08838834764831845f;

  bf16x8 qf[8];
  const u16* qbase = Q + (size_t)(b * 2048 + qg) * 4096 + h * 128 + hi * 8;
#pragma unroll
  for (int kc = 0; kc < 8; ++kc) qf[kc] = *(const bf16x8*)(qbase + kc * 16);

  const int krow = w * 4 + (lane >> 4);
  const int koff = krow * 128 + (((lane & 15) ^ (krow & 7)) * 8);
  const int vrow = w * 8 + (lane >> 3);
  const int voff = vrow * 2560 + (((lane & 7) ^ (vrow & 7)) * 8);
  const u16* kp = Kc + (size_t)(b * 8 + kh) * 2560 * 128;
  const u16* vp = Vt + (size_t)(b * 8 + kh) * 128 * 2560;
  u16* ksd0 = &lds[0][w * 512]; u16* ksd1 = &lds[1][w * 512];
  u16* vsd0 = &lds[0][8192 + w * 512]; u16* vsd1 = &lds[1][8192 + w * 512];

  const int ntiles = 4 * qt + 12;

  gload_lds16(kp + koff, ksd0);
  gload_lds16(kp + koff + 4096, ksd0 + 4096);
  gload_lds16(vp + voff, vsd0);
  gload_lds16(vp + voff + 163840, vsd0 + 4096);

  float m_run = -1e30f, l_run = 0.f;
  f32x16 oacc[4] = {};
  const int s7 = c32 & 7;

  for (int t = 0; t < ntiles; ++t) {
    const int pb = t & 1;
    if (t + 1 < ntiles) {
      u16* kd = pb ? ksd0 : ksd1;
      u16* vd = pb ? vsd0 : vsd1;
      gload_lds16(kp + 8192 + koff, kd);
      gload_lds16(kp + 8192 + koff + 4096, kd + 4096);
      gload_lds16(vp + 64 + voff, vd);
      gload_lds16(vp + 64 + voff + 163840, vd + 4096);
      asm volatile("s_waitcnt vmcnt(4)" ::: "memory");
    } else {
      asm volatile("s_waitcnt vmcnt(0)" ::: "memory");
    }
    __builtin_amdgcn_s_barrier();

    const int dd = 512 + qw - t * 64;
    if (dd >= -31) {
      const u16* Ks = &lds[pb][0];
      const u16* Vs = &lds[pb][8192];

      f32x16 sc[2] = {};
#pragma unroll
      for (int kc = 0; kc < 8; ++kc) {
#pragma unroll
        for (int sb = 0; sb < 2; ++sb) {
          const int sr = sb * 32 + c32;
          bf16x8 kf = *(const bf16x8*)(Ks + sr * 128 + (((kc * 2 + hi) ^ s7) * 8));
          sc[sb] = __builtin_amdgcn_mfma_f32_32x32x16_bf16(kf, qf[kc], sc[sb], 0, 0, 0);
        }
      }

      if (dd < 63) {
        const int base = 4 * hi - c32;
#pragma unroll
        for (int sb = 0; sb < 2; ++sb)
#pragma unroll
          for (int r = 0; r < 16; ++r) {
            const int srow = sb * 32 + (r & 3) + 8 * (r >> 2);
            if (srow + base > dd) sc[sb][r] = -1e30f;
          }
      }

      float pmax = -1e30f;
#pragma unroll
      for (int sb = 0; sb < 2; ++sb)
#pragma unroll
        for (int r = 0; r < 16; ++r) pmax = fmaxf(pmax, sc[sb][r]);
      pmax = crossmax(pmax);

      if (__any(pmax > m_run + 64.f)) {
        const float mn = fmaxf(m_run, pmax);
        const float corr = __expf((m_run - mn) * SCALE);
#pragma unroll
        for (int db = 0; db < 4; ++db)
#pragma unroll
          for (int r = 0; r < 16; ++r) oacc[db][r] *= corr;
        l_run *= corr;
        m_run = mn;
      }

      const float nms = -m_run * SCALE;
      float ls = 0.f;
#pragma unroll
      for (int sb = 0; sb < 2; ++sb)
#pragma unroll
        for (int r = 0; r < 16; ++r) {
          float p = __expf(fmaf(sc[sb][r], SCALE, nms));
          sc[sb][r] = p;
          ls += p;
        }
      l_run += crosssum(ls);

      bf16x8 pa[4];
#pragma unroll
      for (int c = 0; c < 4; ++c) {
        const int sb = c >> 1, bb = (c & 1) * 8;
        u32 a  = cvtpk(sc[sb][bb + 0], sc[sb][bb + 1]);
        u32 b2 = cvtpk(sc[sb][bb + 2], sc[sb][bb + 3]);
        u32 c2 = cvtpk(sc[sb][bb + 4], sc[sb][bb + 5]);
        u32 d2 = cvtpk(sc[sb][bb + 6], sc[sb][bb + 7]);
        plswap(a, c2);
        plswap(b2, d2);
        union { u32 u[4]; bf16x8 v; } cv;
        cv.u[0] = a; cv.u[1] = b2; cv.u[2] = c2; cv.u[3] = d2;
        pa[c] = cv.v;
      }

#pragma unroll
      for (int c = 0; c < 4; ++c) {
#pragma unroll
        for (int db = 0; db < 4; ++db) {
          const int d = db * 32 + c32;
          bf16x8 vf = *(const bf16x8*)(Vs + d * 64 + (((c * 2 + hi) ^ s7) * 8));
          oacc[db] = __builtin_amdgcn_mfma_f32_32x32x16_bf16(vf, pa[c], oacc[db], 0, 0, 0);
        }
      }
    }
    __builtin_amdgcn_s_barrier();
    kp += 8192; vp += 64;
  }

  const float linv = 1.f / l_run;
  u16* ob = Oa + (size_t)(b * 2048 + qg) * 4096 + h * 128 + 4 * hi;
#pragma unroll
  for (int db = 0; db < 4; ++db)
#pragma unroll
    for (int rg = 0; rg < 4; ++rg) {
      u32x2 st;
      st[0] = cvtpk(oacc[db][rg * 4 + 0] * linv, oacc[db][rg * 4 + 1] * linv);
      st[1] = cvtpk(oacc[db][rg * 4 + 2] * linv, oacc[db][rg * 4 + 3] * linv);
      *(u32x2*)(ob + db * 32 + rg * 8) = st;
    }
}

extern "C" void kernel_launch(void* const* d_in, const int* in_sizes, int n_in,
                              void* d_out, int out_size, void* d_ws, size_t ws_size,
                              hipStream_t stream) {
  (void)in_sizes; (void)n_in; (void)out_size; (void)ws_size;
  const float* x  = (const float*)d_in[0];
  const float* pk = (const float*)d_in[2];
  const float* pv = (const float*)d_in[3];
  const float* Wq = (const float*)d_in[4];
  const float* Wk = (const float*)d_in[5];
  const float* Wv = (const float*)d_in[6];
  const float* Wo = (const float*)d_in[7];
  float* out = (float*)d_out;

  char* w = (char*)d_ws;  // peak 132 MB
  u16* xb   = (u16*)(w);               // [0,32M)   x bf16 [4096,4096]; ao aliases later
  u16* wt   = (u16*)(w + 33554432);    // [32M,64M) transposed weights (reused)
  u16* kvb2 = (u16*)(w + 50331648);    // [48M,64M) KV split-K z=1 partial (dead Wq^T zone)
  u16* qb   = (u16*)(w + 67108864);    // [64M,96M) Q bf16 [4096,4096]
  u16* kvb  = (u16*)(w + 100663296);   // [96M,112M) KV split-K z=0 partial [4096,2048]
  u16* kc   = (u16*)(w + 117440512);   // [112M,122M) Kc bf16 [2,8,2560,128]
  u16* vt   = (u16*)(w + 127926272);   // [122M,132M) Vt bf16 [2,8,128,2560]
  u16* ao   = xb;

  cast_x_kernel<<<8192, 256, 0, stream>>>(x, xb);
  transpose_cast<<<dim3(128, 128), 256, 0, stream>>>(Wq, wt, 4096, 4096);
  gemm8<u16><<<dim3(16, 16), 512, 0, stream>>>(xb, wt, qb, qb, 4096, 4096, 4096, 4096);
  transpose_cast<<<dim3(32, 128), 256, 0, stream>>>(Wk, wt, 4096, 1024);
  transpose_cast<<<dim3(32, 128), 256, 0, stream>>>(Wv, wt + (size_t)1024 * 4096, 4096, 1024);
  gemm8<u16><<<dim3(8, 16, 2), 512, 0, stream>>>(xb, wt, kvb, kvb2, 4096, 2048, 2048, 4096);
  kcat<<<2560, 256, 0, stream>>>(pk, kvb, kvb2, kc);
  vt_build<<<dim3(80, 4, 16), 256, 0, stream>>>(pv, kvb, kvb2, vt);
  transpose_cast<<<dim3(128, 128), 256, 0, stream>>>(Wo, wt, 4096, 4096);
  attn_fwd<<<512, 512, 0, stream>>>(qb, kc, vt, ao);
  gemm8<float><<<dim3(16, 16), 512, 0, stream>>>(ao, wt, out, out, 4096, 4096, 4096, 4096);
}